// Round 1
// baseline (635.690 us; speedup 1.0000x reference)
//
#include <hip/hip_runtime.h>

typedef unsigned short u16;
typedef unsigned char  u8;
typedef unsigned int   u32;

typedef short bf16x8 __attribute__((ext_vector_type(8)));
typedef float f32x4  __attribute__((ext_vector_type(4)));

#define DEV __device__ __forceinline__

DEV u16 f2bf(float x) {
  u32 u = __builtin_bit_cast(u32, x);
  u32 r = (u + 0x7fffu + ((u >> 16) & 1u)) >> 16;
  return (u16)r;
}
DEV float bf2f(u16 h) {
  u32 u = ((u32)h) << 16;
  return __builtin_bit_cast(float, u);
}
DEV f32x4 mfma16(bf16x8 a, bf16x8 b, f32x4 c) {
  return __builtin_amdgcn_mfma_f32_16x16x32_bf16(a, b, c, 0, 0, 0);
}

// ---------------------------------------------------------------------------
// 1) split fp32 -> bf16 hi/lo
// ---------------------------------------------------------------------------
__global__ __launch_bounds__(256) void split_kernel(
    const float* __restrict__ x, u16* __restrict__ hi, u16* __restrict__ lo, int n) {
  int i = blockIdx.x * 256 + threadIdx.x;
  if (i >= n) return;
  float v = x[i];
  u16 h = f2bf(v);
  hi[i] = h;
  lo[i] = f2bf(v - bf2f(h));
}

// ---------------------------------------------------------------------------
// 2) ca[h][k] = sum_j W[h*64+j][k] * a[j]   (fp64)
// ---------------------------------------------------------------------------
__global__ __launch_bounds__(256) void ca_kernel(
    const float* __restrict__ W, const float* __restrict__ ha, double* __restrict__ ca) {
  int idx = blockIdx.x * 256 + threadIdx.x;  // 16 * 1024
  int h = idx >> 10, k = idx & 1023;
  double s = 0.0;
#pragma unroll 8
  for (int j = 0; j < 64; ++j)
    s += (double)W[(size_t)(h * 64 + j) * 1024 + k] * (double)ha[j];
  ca[idx] = s;
}

// ---------------------------------------------------------------------------
// 3) d[bh][l] = sum_k hidden[row][k] * ca[h][k]   (fp64 acc; exact q-hash sign)
// ---------------------------------------------------------------------------
__global__ __launch_bounds__(256) void d_kernel(
    const float* __restrict__ hid, const double* __restrict__ ca, float* __restrict__ dq) {
  const int row  = blockIdx.x * 4 + (threadIdx.x >> 6);  // 0..4095
  const int lane = threadIdx.x & 63;
  const int b = row >> 11, l = row & 2047;
  double acc[16];
#pragma unroll
  for (int h = 0; h < 16; ++h) acc[h] = 0.0;
  const float* hp = hid + (size_t)row * 1024;
  for (int k = lane; k < 1024; k += 64) {
    const double hv = (double)hp[k];
#pragma unroll
    for (int h = 0; h < 16; ++h) acc[h] += hv * ca[h * 1024 + k];
  }
#pragma unroll
  for (int h = 0; h < 16; ++h) {
    double v = acc[h];
#pragma unroll
    for (int off = 32; off; off >>= 1) v += __shfl_xor(v, off, 64);
    if (lane == 0) dq[(size_t)(b * 16 + h) * 2048 + l] = (float)v;
  }
}

// ---------------------------------------------------------------------------
// 4) split-bf16 GEMM:  C[m][n] = sum_k A[m][k]*B[n][k] + bias[n]
//    TERMS=3: hi*hi + hi*lo + lo*hi (fp32-grade). TERMS=1: hi*hi (bf16-grade).
//    128x128 tile, BK=32, 256 thr, global_load_lds width-16 staging.
// ---------------------------------------------------------------------------
template <int TERMS>
__global__ __launch_bounds__(256) void gemm_bt(
    const u16* __restrict__ Ahi, const u16* __restrict__ Alo,
    const u16* __restrict__ Bhi, const u16* __restrict__ Blo,
    const float* __restrict__ bias, float* __restrict__ Cf, u16* __restrict__ Cb) {
  constexpr int K = 1024, N = 1024;
  __shared__ u16 Ah[128 * 32];
  __shared__ u16 Bh[128 * 32];
  __shared__ u16 Al[TERMS > 1 ? 128 * 32 : 64];
  __shared__ u16 Bl[TERMS > 1 ? 128 * 32 : 64];
  const int tid = threadIdx.x;
  const int wave = tid >> 6, lane = tid & 63;
  const int quad = lane >> 4, lm = lane & 15;
  const int wr = wave >> 1, wc = wave & 1;
  const int m0 = blockIdx.x * 128, n0 = blockIdx.y * 128;

  f32x4 acc[4][4];
#pragma unroll
  for (int i = 0; i < 4; ++i)
#pragma unroll
    for (int j = 0; j < 4; ++j) acc[i][j] = {0.f, 0.f, 0.f, 0.f};

  for (int k0 = 0; k0 < K; k0 += 32) {
    __syncthreads();
#pragma unroll
    for (int it = 0; it < 2; ++it) {
      const int rb = wave * 2 + it;               // 16-row chunk id, wave-uniform
      const int row = rb * 16 + (lane >> 2);
      const int ch = lane & 3;
      const size_t goffA = (size_t)(m0 + row) * K + k0 + ch * 8;
      const size_t goffB = (size_t)(n0 + row) * K + k0 + ch * 8;
      __builtin_amdgcn_global_load_lds(
          (const __attribute__((address_space(1))) void*)(Ahi + goffA),
          (__attribute__((address_space(3))) void*)(Ah + rb * 512), 16, 0, 0);
      __builtin_amdgcn_global_load_lds(
          (const __attribute__((address_space(1))) void*)(Bhi + goffB),
          (__attribute__((address_space(3))) void*)(Bh + rb * 512), 16, 0, 0);
      if constexpr (TERMS > 1) {
        __builtin_amdgcn_global_load_lds(
            (const __attribute__((address_space(1))) void*)(Alo + goffA),
            (__attribute__((address_space(3))) void*)(Al + rb * 512), 16, 0, 0);
        __builtin_amdgcn_global_load_lds(
            (const __attribute__((address_space(1))) void*)(Blo + goffB),
            (__attribute__((address_space(3))) void*)(Bl + rb * 512), 16, 0, 0);
      }
    }
    __syncthreads();

    bf16x8 a_h[4], b_h[4], a_l[4], b_l[4];
#pragma unroll
    for (int i = 0; i < 4; ++i)
      a_h[i] = *(const bf16x8*)(Ah + (wr * 64 + i * 16 + lm) * 32 + quad * 8);
#pragma unroll
    for (int j = 0; j < 4; ++j)
      b_h[j] = *(const bf16x8*)(Bh + (wc * 64 + j * 16 + lm) * 32 + quad * 8);
    if constexpr (TERMS > 1) {
#pragma unroll
      for (int i = 0; i < 4; ++i)
        a_l[i] = *(const bf16x8*)(Al + (wr * 64 + i * 16 + lm) * 32 + quad * 8);
#pragma unroll
      for (int j = 0; j < 4; ++j)
        b_l[j] = *(const bf16x8*)(Bl + (wc * 64 + j * 16 + lm) * 32 + quad * 8);
    }
#pragma unroll
    for (int i = 0; i < 4; ++i)
#pragma unroll
      for (int j = 0; j < 4; ++j) {
        acc[i][j] = mfma16(a_h[i], b_h[j], acc[i][j]);
        if constexpr (TERMS > 1) {
          acc[i][j] = mfma16(a_h[i], b_l[j], acc[i][j]);
          acc[i][j] = mfma16(a_l[i], b_h[j], acc[i][j]);
        }
      }
  }

  // epilogue: C layout col=lane&15, row=quad*4+r (m89/m91 verified)
#pragma unroll
  for (int i = 0; i < 4; ++i)
#pragma unroll
    for (int j = 0; j < 4; ++j) {
      const int col = n0 + wc * 64 + j * 16 + lm;
      const float bv = bias[col];
#pragma unroll
      for (int r = 0; r < 4; ++r) {
        const int row = m0 + wr * 64 + i * 16 + quad * 4 + r;
        const float val = acc[i][j][r] + bv;
        const size_t idx = (size_t)row * N + col;
        if (Cf) Cf[idx] = val;
        Cb[idx] = f2bf(val);
      }
    }
}

// ---------------------------------------------------------------------------
// 5) per-(b,h): n2, max-norm, hash bits
// ---------------------------------------------------------------------------
__global__ __launch_bounds__(256) void stats_kernel(
    const float* __restrict__ qk, const float* __restrict__ dq,
    const float* __restrict__ ha, u8* __restrict__ hqA, u8* __restrict__ hkA) {
  const int bh = blockIdx.x;
  const int b = bh >> 4, h = bh & 15;
  const int tid = threadIdx.x;
  const int wave = tid >> 6, lane = tid & 63;
  __shared__ float n2s[2048];
  __shared__ float red[4];
  float lmax = 0.f;
  for (int l = wave; l < 2048; l += 4) {
    float v = qk[(size_t)(b * 2048 + l) * 1024 + h * 64 + lane];
    float sq = v * v;
#pragma unroll
    for (int off = 32; off; off >>= 1) sq += __shfl_xor(sq, off, 64);
    if (lane == 0) n2s[l] = sq;
    lmax = fmaxf(lmax, sq);
  }
  if (lane == 0) red[wave] = lmax;
  __syncthreads();
  const float maxn2 = fmaxf(fmaxf(red[0], red[1]), fmaxf(red[2], red[3]));
  const float s = 0.75f / fmaxf(sqrtf(maxn2), 1e-12f);
  const float a64 = ha[64], a65 = ha[65];
  for (int l = tid; l < 2048; l += 256) {
    const float dv = dq[(size_t)bh * 2048 + l];
    const float n2 = n2s[l];
    const float nk2 = s * s * n2;
    const float hkdot = s * dv + (0.5f - nk2) * a64 + (0.5f - nk2 * nk2) * a65;
    hqA[(size_t)bh * 2048 + l] = (dv >= 0.f) ? 1 : 0;
    hkA[(size_t)bh * 2048 + l] = (hkdot >= 0.f) ? 1 : 0;
  }
}

// ---------------------------------------------------------------------------
// 6) flash attention, 64q x 64k tiles, bf16 MFMA, online softmax + LSH mask
// ---------------------------------------------------------------------------
__global__ __launch_bounds__(256) void attn_kernel(
    const u16* __restrict__ qkb, const u16* __restrict__ vb,
    const u8* __restrict__ hqA, const u8* __restrict__ hkA, float* __restrict__ out) {
  constexpr int STR = 72;  // padded row stride (u16) -> 2-way bank aliasing only
  const int qt = blockIdx.x;  // 0..31
  const int bh = blockIdx.y;  // 0..31
  const int b = bh >> 4, h = bh & 15;
  const int tid = threadIdx.x;
  const int wave = tid >> 6, lane = tid & 63;
  const int quad = lane >> 4, lm = lane & 15;

  __shared__ u16 Qs[64 * STR];
  __shared__ u16 Ks[64 * STR];
  __shared__ u16 Vs[64 * STR];   // transposed: Vs[dh][key]
  __shared__ u16 Ps[4][16 * STR];
  __shared__ u8 hqs[64];
  __shared__ u8 hks[64];

  const size_t base = (size_t)b * 2048 * 1024 + h * 64;
  const u16* qbase = qkb + base;
  const u16* vbase = vb + base;
  const int q0 = qt * 64;

  {
    const int row0 = tid >> 3, ch = tid & 7;
#pragma unroll
    for (int it = 0; it < 2; ++it) {
      const int row = row0 + it * 32;
      uint4 v = *(const uint4*)(qbase + (size_t)(q0 + row) * 1024 + ch * 8);
      *(uint4*)((char*)Qs + row * (STR * 2) + ch * 16) = v;
    }
  }
  if (tid < 16)
    ((u32*)hqs)[tid] = ((const u32*)(hqA + (size_t)bh * 2048 + q0))[tid];
  __syncthreads();

  // invariant Q A-frags: A[m=lane&15][k=quad*8+j]
  bf16x8 aQ0 = *(const bf16x8*)(Qs + (wave * 16 + lm) * STR + quad * 8);
  bf16x8 aQ1 = *(const bf16x8*)(Qs + (wave * 16 + lm) * STR + 32 + quad * 8);
  u8 hqb[4];
#pragma unroll
  for (int r = 0; r < 4; ++r) hqb[r] = hqs[wave * 16 + quad * 4 + r];

  float m_i[4], l_i[4];
  f32x4 acc_o[4];
#pragma unroll
  for (int r = 0; r < 4; ++r) { m_i[r] = -1e30f; l_i[r] = 0.f; }
#pragma unroll
  for (int j = 0; j < 4; ++j) acc_o[j] = {0.f, 0.f, 0.f, 0.f};

  for (int kt = 0; kt < 32; ++kt) {
    const int k0 = kt * 64;
    __syncthreads();  // protect K/V/hks from previous iteration's readers
    {
      const int row0 = tid >> 3, ch = tid & 7;
#pragma unroll
      for (int it = 0; it < 2; ++it) {
        const int row = row0 + it * 32;
        uint4 kv = *(const uint4*)(qbase + (size_t)(k0 + row) * 1024 + ch * 8);
        *(uint4*)((char*)Ks + row * (STR * 2) + ch * 16) = kv;
        union { uint4 v; u16 s[8]; } u;
        u.v = *(const uint4*)(vbase + (size_t)(k0 + row) * 1024 + ch * 8);
#pragma unroll
        for (int j = 0; j < 8; ++j) Vs[(ch * 8 + j) * STR + row] = u.s[j];
      }
    }
    if (tid < 16)
      ((u32*)hks)[tid] = ((const u32*)(hkA + (size_t)bh * 2048 + k0))[tid];
    __syncthreads();

    // S = Q K^T * 0.125 + mask
    float sv[4][4];
#pragma unroll
    for (int n = 0; n < 4; ++n) {
      bf16x8 b0 = *(const bf16x8*)(Ks + (n * 16 + lm) * STR + quad * 8);
      bf16x8 b1 = *(const bf16x8*)(Ks + (n * 16 + lm) * STR + 32 + quad * 8);
      f32x4 c = {0.f, 0.f, 0.f, 0.f};
      c = mfma16(aQ0, b0, c);
      c = mfma16(aQ1, b1, c);
      const u8 hkb = hks[n * 16 + lm];
#pragma unroll
      for (int r = 0; r < 4; ++r)
        sv[n][r] = c[r] * 0.125f + ((hqb[r] == hkb) ? 0.f : -1e4f);
    }
    // online softmax
    float alpha[4], rsum[4];
#pragma unroll
    for (int r = 0; r < 4; ++r) {
      float mx = fmaxf(fmaxf(sv[0][r], sv[1][r]), fmaxf(sv[2][r], sv[3][r]));
#pragma unroll
      for (int off = 1; off < 16; off <<= 1) mx = fmaxf(mx, __shfl_xor(mx, off, 64));
      const float mn = fmaxf(m_i[r], mx);
      alpha[r] = __expf(m_i[r] - mn);
      m_i[r] = mn;
      rsum[r] = 0.f;
    }
#pragma unroll
    for (int n = 0; n < 4; ++n)
#pragma unroll
      for (int r = 0; r < 4; ++r) {
        const float p = __expf(sv[n][r] - m_i[r]);
        rsum[r] += p;
        Ps[wave][(quad * 4 + r) * STR + n * 16 + lm] = f2bf(p);
      }
#pragma unroll
    for (int r = 0; r < 4; ++r) {
      float s = rsum[r];
#pragma unroll
      for (int off = 1; off < 16; off <<= 1) s += __shfl_xor(s, off, 64);
      l_i[r] = l_i[r] * alpha[r] + s;
    }
#pragma unroll
    for (int j = 0; j < 4; ++j)
#pragma unroll
      for (int r = 0; r < 4; ++r) acc_o[j][r] *= alpha[r];

    __syncthreads();  // order P LDS write -> A-frag read

    bf16x8 aP0 = *(const bf16x8*)(&Ps[wave][lm * STR + quad * 8]);
    bf16x8 aP1 = *(const bf16x8*)(&Ps[wave][lm * STR + 32 + quad * 8]);
#pragma unroll
    for (int j = 0; j < 4; ++j) {
      bf16x8 v0 = *(const bf16x8*)(Vs + (j * 16 + lm) * STR + quad * 8);
      bf16x8 v1 = *(const bf16x8*)(Vs + (j * 16 + lm) * STR + 32 + quad * 8);
      acc_o[j] = mfma16(aP0, v0, acc_o[j]);
      acc_o[j] = mfma16(aP1, v1, acc_o[j]);
    }
  }

#pragma unroll
  for (int r = 0; r < 4; ++r) {
    const float inv = 1.0f / l_i[r];
    const int row = q0 + wave * 16 + quad * 4 + r;
    float* op = out + (size_t)(b * 2048 + row) * 1024 + h * 64;
#pragma unroll
    for (int j = 0; j < 4; ++j) op[j * 16 + lm] = acc_o[j][r] * inv;
  }
}

// ---------------------------------------------------------------------------
extern "C" void kernel_launch(void* const* d_in, const int* in_sizes, int n_in,
                              void* d_out, int out_size, void* d_ws, size_t ws_size,
                              hipStream_t stream) {
  const float* hidden = (const float*)d_in[0];
  const float* qk_w   = (const float*)d_in[1];
  const float* qk_b   = (const float*)d_in[2];
  const float* v_w    = (const float*)d_in[3];
  const float* v_b    = (const float*)d_in[4];
  const float* hash_a = (const float*)d_in[5];
  float* out = (float*)d_out;

  char* base = (char*)d_ws;
  size_t off = 0;
  auto take = [&](size_t bytes) -> char* {
    char* r = base + off;
    off += (bytes + 255) & ~(size_t)255;
    return r;
  };
  const size_t NH = 4194304;  // B*L*D
  const size_t NW = 1048576;  // D*D
  u16* hHi  = (u16*)take(NH * 2);
  u16* hLo  = (u16*)take(NH * 2);
  u16* wqHi = (u16*)take(NW * 2);
  u16* wqLo = (u16*)take(NW * 2);
  u16* wvHi = (u16*)take(NW * 2);
  u16* wvLo = (u16*)take(NW * 2);
  float* qkF = (float*)take(NH * 4);
  u16* qkB  = (u16*)take(NH * 2);
  u16* vB   = (u16*)take(NH * 2);
  double* ca = (double*)take(16 * 1024 * 8);
  float* dq  = (float*)take(65536 * 4);
  u8* hqA = (u8*)take(65536);
  u8* hkA = (u8*)take(65536);

  hipLaunchKernelGGL(split_kernel, dim3(NH / 256), dim3(256), 0, stream, hidden, hHi, hLo, (int)NH);
  hipLaunchKernelGGL(split_kernel, dim3(NW / 256), dim3(256), 0, stream, qk_w, wqHi, wqLo, (int)NW);
  hipLaunchKernelGGL(split_kernel, dim3(NW / 256), dim3(256), 0, stream, v_w, wvHi, wvLo, (int)NW);
  hipLaunchKernelGGL(ca_kernel, dim3(64), dim3(256), 0, stream, qk_w, hash_a, ca);
  hipLaunchKernelGGL(d_kernel, dim3(1024), dim3(256), 0, stream, hidden, ca, dq);
  hipLaunchKernelGGL((gemm_bt<3>), dim3(32, 8), dim3(256), 0, stream, hHi, hLo, wqHi, wqLo, qk_b, qkF, qkB);
  hipLaunchKernelGGL((gemm_bt<1>), dim3(32, 8), dim3(256), 0, stream, hHi, (const u16*)nullptr, wvHi,
                     (const u16*)nullptr, v_b, (float*)nullptr, vB);
  hipLaunchKernelGGL(stats_kernel, dim3(32), dim3(256), 0, stream, qkF, dq, hash_a, hqA, hkA);
  hipLaunchKernelGGL(attn_kernel, dim3(32, 32), dim3(256), 0, stream, qkB, vB, hqA, hkA, out);
}

// Round 2
// 374.534 us; speedup vs baseline: 1.6973x; 1.6973x over previous
//
#include <hip/hip_runtime.h>

typedef unsigned short u16;
typedef unsigned char  u8;
typedef unsigned int   u32;

typedef short bf16x8 __attribute__((ext_vector_type(8)));
typedef float f32x4  __attribute__((ext_vector_type(4)));

#define DEV __device__ __forceinline__

DEV u16 f2bf(float x) {
  u32 u = __builtin_bit_cast(u32, x);
  u32 r = (u + 0x7fffu + ((u >> 16) & 1u)) >> 16;
  return (u16)r;
}
DEV float bf2f(u16 h) {
  u32 u = ((u32)h) << 16;
  return __builtin_bit_cast(float, u);
}
DEV f32x4 mfma16(bf16x8 a, bf16x8 b, f32x4 c) {
  return __builtin_amdgcn_mfma_f32_16x16x32_bf16(a, b, c, 0, 0, 0);
}

// ---------------------------------------------------------------------------
// 1) split fp32 -> bf16 hi/lo
// ---------------------------------------------------------------------------
__global__ __launch_bounds__(256) void split_kernel(
    const float* __restrict__ x, u16* __restrict__ hi, u16* __restrict__ lo, int n) {
  int i = blockIdx.x * 256 + threadIdx.x;
  if (i >= n) return;
  float v = x[i];
  u16 h = f2bf(v);
  hi[i] = h;
  lo[i] = f2bf(v - bf2f(h));
}

// ---------------------------------------------------------------------------
// 2) ca[h][k] = sum_j W[h*64+j][k] * a[j]   (fp64)
// ---------------------------------------------------------------------------
__global__ __launch_bounds__(256) void ca_kernel(
    const float* __restrict__ W, const float* __restrict__ ha, double* __restrict__ ca) {
  int idx = blockIdx.x * 256 + threadIdx.x;  // 16 * 1024
  int h = idx >> 10, k = idx & 1023;
  double s = 0.0;
#pragma unroll 8
  for (int j = 0; j < 64; ++j)
    s += (double)W[(size_t)(h * 64 + j) * 1024 + k] * (double)ha[j];
  ca[idx] = s;
}

// ---------------------------------------------------------------------------
// 3) d[bh][l] = sum_k hidden[row][k] * ca[h][k]   (fp64 acc; exact q-hash sign)
// ---------------------------------------------------------------------------
__global__ __launch_bounds__(256) void d_kernel(
    const float* __restrict__ hid, const double* __restrict__ ca, float* __restrict__ dq) {
  const int row  = blockIdx.x * 4 + (threadIdx.x >> 6);  // 0..4095
  const int lane = threadIdx.x & 63;
  const int b = row >> 11, l = row & 2047;
  double acc[16];
#pragma unroll
  for (int h = 0; h < 16; ++h) acc[h] = 0.0;
  const float* hp = hid + (size_t)row * 1024;
  for (int k = lane; k < 1024; k += 64) {
    const double hv = (double)hp[k];
#pragma unroll
    for (int h = 0; h < 16; ++h) acc[h] += hv * ca[h * 1024 + k];
  }
#pragma unroll
  for (int h = 0; h < 16; ++h) {
    double v = acc[h];
#pragma unroll
    for (int off = 32; off; off >>= 1) v += __shfl_xor(v, off, 64);
    if (lane == 0) dq[(size_t)(b * 16 + h) * 2048 + l] = (float)v;
  }
}

// ---------------------------------------------------------------------------
// 4) split-bf16 GEMM:  C[m][n] = sum_k A[m][k]*B[n][k] + bias[n]
//    TERMS=3: hi*hi + hi*lo + lo*hi (fp32-grade). TERMS=1: hi*hi (bf16-grade).
//    128x128 tile, BK=32, 256 thr, global_load_lds width-16 staging.
// ---------------------------------------------------------------------------
template <int TERMS>
__global__ __launch_bounds__(256) void gemm_bt(
    const u16* __restrict__ Ahi, const u16* __restrict__ Alo,
    const u16* __restrict__ Bhi, const u16* __restrict__ Blo,
    const float* __restrict__ bias, float* __restrict__ Cf, u16* __restrict__ Cb) {
  constexpr int K = 1024, N = 1024;
  __shared__ u16 Ah[128 * 32];
  __shared__ u16 Bh[128 * 32];
  __shared__ u16 Al[TERMS > 1 ? 128 * 32 : 64];
  __shared__ u16 Bl[TERMS > 1 ? 128 * 32 : 64];
  const int tid = threadIdx.x;
  const int wave = tid >> 6, lane = tid & 63;
  const int quad = lane >> 4, lm = lane & 15;
  const int wr = wave >> 1, wc = wave & 1;
  const int m0 = blockIdx.x * 128, n0 = blockIdx.y * 128;

  f32x4 acc[4][4];
#pragma unroll
  for (int i = 0; i < 4; ++i)
#pragma unroll
    for (int j = 0; j < 4; ++j) acc[i][j] = {0.f, 0.f, 0.f, 0.f};

  for (int k0 = 0; k0 < K; k0 += 32) {
    __syncthreads();
#pragma unroll
    for (int it = 0; it < 2; ++it) {
      const int rb = wave * 2 + it;               // 16-row chunk id, wave-uniform
      const int row = rb * 16 + (lane >> 2);
      const int ch = lane & 3;
      const size_t goffA = (size_t)(m0 + row) * K + k0 + ch * 8;
      const size_t goffB = (size_t)(n0 + row) * K + k0 + ch * 8;
      __builtin_amdgcn_global_load_lds(
          (const __attribute__((address_space(1))) void*)(Ahi + goffA),
          (__attribute__((address_space(3))) void*)(Ah + rb * 512), 16, 0, 0);
      __builtin_amdgcn_global_load_lds(
          (const __attribute__((address_space(1))) void*)(Bhi + goffB),
          (__attribute__((address_space(3))) void*)(Bh + rb * 512), 16, 0, 0);
      if constexpr (TERMS > 1) {
        __builtin_amdgcn_global_load_lds(
            (const __attribute__((address_space(1))) void*)(Alo + goffA),
            (__attribute__((address_space(3))) void*)(Al + rb * 512), 16, 0, 0);
        __builtin_amdgcn_global_load_lds(
            (const __attribute__((address_space(1))) void*)(Blo + goffB),
            (__attribute__((address_space(3))) void*)(Bl + rb * 512), 16, 0, 0);
      }
    }
    __syncthreads();

    bf16x8 a_h[4], b_h[4], a_l[4], b_l[4];
#pragma unroll
    for (int i = 0; i < 4; ++i)
      a_h[i] = *(const bf16x8*)(Ah + (wr * 64 + i * 16 + lm) * 32 + quad * 8);
#pragma unroll
    for (int j = 0; j < 4; ++j)
      b_h[j] = *(const bf16x8*)(Bh + (wc * 64 + j * 16 + lm) * 32 + quad * 8);
    if constexpr (TERMS > 1) {
#pragma unroll
      for (int i = 0; i < 4; ++i)
        a_l[i] = *(const bf16x8*)(Al + (wr * 64 + i * 16 + lm) * 32 + quad * 8);
#pragma unroll
      for (int j = 0; j < 4; ++j)
        b_l[j] = *(const bf16x8*)(Bl + (wc * 64 + j * 16 + lm) * 32 + quad * 8);
    }
#pragma unroll
    for (int i = 0; i < 4; ++i)
#pragma unroll
      for (int j = 0; j < 4; ++j) {
        acc[i][j] = mfma16(a_h[i], b_h[j], acc[i][j]);
        if constexpr (TERMS > 1) {
          acc[i][j] = mfma16(a_h[i], b_l[j], acc[i][j]);
          acc[i][j] = mfma16(a_l[i], b_h[j], acc[i][j]);
        }
      }
  }

  // epilogue: C layout col=lane&15, row=quad*4+r (m89/m91 verified)
#pragma unroll
  for (int i = 0; i < 4; ++i)
#pragma unroll
    for (int j = 0; j < 4; ++j) {
      const int col = n0 + wc * 64 + j * 16 + lm;
      const float bv = bias[col];
#pragma unroll
      for (int r = 0; r < 4; ++r) {
        const int row = m0 + wr * 64 + i * 16 + quad * 4 + r;
        const float val = acc[i][j][r] + bv;
        const size_t idx = (size_t)row * N + col;
        if (Cf) Cf[idx] = val;
        Cb[idx] = f2bf(val);
      }
    }
}

// ---------------------------------------------------------------------------
// 5a) n2[bh][l] = sum over the head's 64 dims of qk^2.
//     One block per (b,l) row; thread t owns float4 at col 4t; head = t/16.
// ---------------------------------------------------------------------------
__global__ __launch_bounds__(256) void norm_kernel(
    const float* __restrict__ qkF, float* __restrict__ n2A) {
  const int row = blockIdx.x;  // b*2048 + l
  const int tid = threadIdx.x;
  float4 v = ((const float4*)(qkF + (size_t)row * 1024))[tid];
  float s = v.x * v.x + v.y * v.y + v.z * v.z + v.w * v.w;
#pragma unroll
  for (int off = 1; off < 16; off <<= 1) s += __shfl_xor(s, off, 64);
  if ((tid & 15) == 0) {
    const int h = tid >> 4;
    const int b = row >> 11, l = row & 2047;
    n2A[(size_t)(b * 16 + h) * 2048 + l] = s;
  }
}

// ---------------------------------------------------------------------------
// 5b) per-(b,h): max-reduce n2, then hash bits. One block per bh (tiny).
// ---------------------------------------------------------------------------
__global__ __launch_bounds__(256) void bits_kernel(
    const float* __restrict__ n2A, const float* __restrict__ dq,
    const float* __restrict__ ha, u8* __restrict__ hqA, u8* __restrict__ hkA) {
  const int bh = blockIdx.x;
  const int tid = threadIdx.x;
  const int wave = tid >> 6, lane = tid & 63;
  __shared__ float red[4];
  const float* n2p = n2A + (size_t)bh * 2048;
  float4 v0 = ((const float4*)n2p)[tid];
  float4 v1 = ((const float4*)n2p)[tid + 256];
  float lmax = fmaxf(fmaxf(fmaxf(v0.x, v0.y), fmaxf(v0.z, v0.w)),
                     fmaxf(fmaxf(v1.x, v1.y), fmaxf(v1.z, v1.w)));
#pragma unroll
  for (int off = 1; off < 64; off <<= 1) lmax = fmaxf(lmax, __shfl_xor(lmax, off, 64));
  if (lane == 0) red[wave] = lmax;
  __syncthreads();
  const float maxn2 = fmaxf(fmaxf(red[0], red[1]), fmaxf(red[2], red[3]));
  const float s = 0.75f / fmaxf(sqrtf(maxn2), 1e-12f);
  const float a64 = ha[64], a65 = ha[65];
#pragma unroll
  for (int it = 0; it < 8; ++it) {
    const int l = it * 256 + tid;
    const float dv = dq[(size_t)bh * 2048 + l];
    const float n2 = n2p[l];
    const float nk2 = s * s * n2;
    const float hkdot = s * dv + (0.5f - nk2) * a64 + (0.5f - nk2 * nk2) * a65;
    hqA[(size_t)bh * 2048 + l] = (dv >= 0.f) ? 1 : 0;
    hkA[(size_t)bh * 2048 + l] = (hkdot >= 0.f) ? 1 : 0;
  }
}

// ---------------------------------------------------------------------------
// 6) flash attention, 64q x 64k tiles, bf16 MFMA, online softmax + LSH mask
// ---------------------------------------------------------------------------
__global__ __launch_bounds__(256) void attn_kernel(
    const u16* __restrict__ qkb, const u16* __restrict__ vb,
    const u8* __restrict__ hqA, const u8* __restrict__ hkA, float* __restrict__ out) {
  constexpr int STR = 72;  // padded row stride (u16) -> 2-way bank aliasing only
  const int qt = blockIdx.x;  // 0..31
  const int bh = blockIdx.y;  // 0..31
  const int b = bh >> 4, h = bh & 15;
  const int tid = threadIdx.x;
  const int wave = tid >> 6, lane = tid & 63;
  const int quad = lane >> 4, lm = lane & 15;

  __shared__ u16 Qs[64 * STR];
  __shared__ u16 Ks[64 * STR];
  __shared__ u16 Vs[64 * STR];   // transposed: Vs[dh][key]
  __shared__ u16 Ps[4][16 * STR];
  __shared__ u8 hqs[64];
  __shared__ u8 hks[64];

  const size_t base = (size_t)b * 2048 * 1024 + h * 64;
  const u16* qbase = qkb + base;
  const u16* vbase = vb + base;
  const int q0 = qt * 64;

  {
    const int row0 = tid >> 3, ch = tid & 7;
#pragma unroll
    for (int it = 0; it < 2; ++it) {
      const int row = row0 + it * 32;
      uint4 v = *(const uint4*)(qbase + (size_t)(q0 + row) * 1024 + ch * 8);
      *(uint4*)((char*)Qs + row * (STR * 2) + ch * 16) = v;
    }
  }
  if (tid < 16)
    ((u32*)hqs)[tid] = ((const u32*)(hqA + (size_t)bh * 2048 + q0))[tid];
  __syncthreads();

  // invariant Q A-frags: A[m=lane&15][k=quad*8+j]
  bf16x8 aQ0 = *(const bf16x8*)(Qs + (wave * 16 + lm) * STR + quad * 8);
  bf16x8 aQ1 = *(const bf16x8*)(Qs + (wave * 16 + lm) * STR + 32 + quad * 8);
  u8 hqb[4];
#pragma unroll
  for (int r = 0; r < 4; ++r) hqb[r] = hqs[wave * 16 + quad * 4 + r];

  float m_i[4], l_i[4];
  f32x4 acc_o[4];
#pragma unroll
  for (int r = 0; r < 4; ++r) { m_i[r] = -1e30f; l_i[r] = 0.f; }
#pragma unroll
  for (int j = 0; j < 4; ++j) acc_o[j] = {0.f, 0.f, 0.f, 0.f};

  for (int kt = 0; kt < 32; ++kt) {
    const int k0 = kt * 64;
    __syncthreads();  // protect K/V/hks from previous iteration's readers
    {
      const int row0 = tid >> 3, ch = tid & 7;
#pragma unroll
      for (int it = 0; it < 2; ++it) {
        const int row = row0 + it * 32;
        uint4 kv = *(const uint4*)(qbase + (size_t)(k0 + row) * 1024 + ch * 8);
        *(uint4*)((char*)Ks + row * (STR * 2) + ch * 16) = kv;
        union { uint4 v; u16 s[8]; } u;
        u.v = *(const uint4*)(vbase + (size_t)(k0 + row) * 1024 + ch * 8);
#pragma unroll
        for (int j = 0; j < 8; ++j) Vs[(ch * 8 + j) * STR + row] = u.s[j];
      }
    }
    if (tid < 16)
      ((u32*)hks)[tid] = ((const u32*)(hkA + (size_t)bh * 2048 + k0))[tid];
    __syncthreads();

    // S = Q K^T * 0.125 + mask
    float sv[4][4];
#pragma unroll
    for (int n = 0; n < 4; ++n) {
      bf16x8 b0 = *(const bf16x8*)(Ks + (n * 16 + lm) * STR + quad * 8);
      bf16x8 b1 = *(const bf16x8*)(Ks + (n * 16 + lm) * STR + 32 + quad * 8);
      f32x4 c = {0.f, 0.f, 0.f, 0.f};
      c = mfma16(aQ0, b0, c);
      c = mfma16(aQ1, b1, c);
      const u8 hkb = hks[n * 16 + lm];
#pragma unroll
      for (int r = 0; r < 4; ++r)
        sv[n][r] = c[r] * 0.125f + ((hqb[r] == hkb) ? 0.f : -1e4f);
    }
    // online softmax
    float alpha[4], rsum[4];
#pragma unroll
    for (int r = 0; r < 4; ++r) {
      float mx = fmaxf(fmaxf(sv[0][r], sv[1][r]), fmaxf(sv[2][r], sv[3][r]));
#pragma unroll
      for (int off = 1; off < 16; off <<= 1) mx = fmaxf(mx, __shfl_xor(mx, off, 64));
      const float mn = fmaxf(m_i[r], mx);
      alpha[r] = __expf(m_i[r] - mn);
      m_i[r] = mn;
      rsum[r] = 0.f;
    }
#pragma unroll
    for (int n = 0; n < 4; ++n)
#pragma unroll
      for (int r = 0; r < 4; ++r) {
        const float p = __expf(sv[n][r] - m_i[r]);
        rsum[r] += p;
        Ps[wave][(quad * 4 + r) * STR + n * 16 + lm] = f2bf(p);
      }
#pragma unroll
    for (int r = 0; r < 4; ++r) {
      float s = rsum[r];
#pragma unroll
      for (int off = 1; off < 16; off <<= 1) s += __shfl_xor(s, off, 64);
      l_i[r] = l_i[r] * alpha[r] + s;
    }
#pragma unroll
    for (int j = 0; j < 4; ++j)
#pragma unroll
      for (int r = 0; r < 4; ++r) acc_o[j][r] *= alpha[r];

    __syncthreads();  // order P LDS write -> A-frag read

    bf16x8 aP0 = *(const bf16x8*)(&Ps[wave][lm * STR + quad * 8]);
    bf16x8 aP1 = *(const bf16x8*)(&Ps[wave][lm * STR + 32 + quad * 8]);
#pragma unroll
    for (int j = 0; j < 4; ++j) {
      bf16x8 v0 = *(const bf16x8*)(Vs + (j * 16 + lm) * STR + quad * 8);
      bf16x8 v1 = *(const bf16x8*)(Vs + (j * 16 + lm) * STR + 32 + quad * 8);
      acc_o[j] = mfma16(aP0, v0, acc_o[j]);
      acc_o[j] = mfma16(aP1, v1, acc_o[j]);
    }
  }

#pragma unroll
  for (int r = 0; r < 4; ++r) {
    const float inv = 1.0f / l_i[r];
    const int row = q0 + wave * 16 + quad * 4 + r;
    float* op = out + (size_t)(b * 2048 + row) * 1024 + h * 64;
#pragma unroll
    for (int j = 0; j < 4; ++j) op[j * 16 + lm] = acc_o[j][r] * inv;
  }
}

// ---------------------------------------------------------------------------
extern "C" void kernel_launch(void* const* d_in, const int* in_sizes, int n_in,
                              void* d_out, int out_size, void* d_ws, size_t ws_size,
                              hipStream_t stream) {
  const float* hidden = (const float*)d_in[0];
  const float* qk_w   = (const float*)d_in[1];
  const float* qk_b   = (const float*)d_in[2];
  const float* v_w    = (const float*)d_in[3];
  const float* v_b    = (const float*)d_in[4];
  const float* hash_a = (const float*)d_in[5];
  float* out = (float*)d_out;

  char* base = (char*)d_ws;
  size_t off = 0;
  auto take = [&](size_t bytes) -> char* {
    char* r = base + off;
    off += (bytes + 255) & ~(size_t)255;
    return r;
  };
  const size_t NH = 4194304;  // B*L*D
  const size_t NW = 1048576;  // D*D
  u16* hHi  = (u16*)take(NH * 2);
  u16* hLo  = (u16*)take(NH * 2);
  u16* wqHi = (u16*)take(NW * 2);
  u16* wqLo = (u16*)take(NW * 2);
  u16* wvHi = (u16*)take(NW * 2);
  u16* wvLo = (u16*)take(NW * 2);
  float* qkF = (float*)take(NH * 4);
  u16* qkB  = (u16*)take(NH * 2);
  u16* vB   = (u16*)take(NH * 2);
  double* ca = (double*)take(16 * 1024 * 8);
  float* dq  = (float*)take(65536 * 4);
  float* n2A = (float*)take(65536 * 4);
  u8* hqA = (u8*)take(65536);
  u8* hkA = (u8*)take(65536);

  hipLaunchKernelGGL(split_kernel, dim3(NH / 256), dim3(256), 0, stream, hidden, hHi, hLo, (int)NH);
  hipLaunchKernelGGL(split_kernel, dim3(NW / 256), dim3(256), 0, stream, qk_w, wqHi, wqLo, (int)NW);
  hipLaunchKernelGGL(split_kernel, dim3(NW / 256), dim3(256), 0, stream, v_w, wvHi, wvLo, (int)NW);
  hipLaunchKernelGGL(ca_kernel, dim3(64), dim3(256), 0, stream, qk_w, hash_a, ca);
  hipLaunchKernelGGL(d_kernel, dim3(1024), dim3(256), 0, stream, hidden, ca, dq);
  hipLaunchKernelGGL((gemm_bt<3>), dim3(32, 8), dim3(256), 0, stream, hHi, hLo, wqHi, wqLo, qk_b, qkF, qkB);
  hipLaunchKernelGGL((gemm_bt<1>), dim3(32, 8), dim3(256), 0, stream, hHi, (const u16*)nullptr, wvHi,
                     (const u16*)nullptr, v_b, (float*)nullptr, vB);
  hipLaunchKernelGGL(norm_kernel, dim3(4096), dim3(256), 0, stream, qkF, n2A);
  hipLaunchKernelGGL(bits_kernel, dim3(32), dim3(256), 0, stream, n2A, dq, hash_a, hqA, hkA);
  hipLaunchKernelGGL(attn_kernel, dim3(32, 32), dim3(256), 0, stream, qkB, vB, hqA, hkA, out);
}

// Round 3
// 325.183 us; speedup vs baseline: 1.9549x; 1.1518x over previous
//
#include <hip/hip_runtime.h>

typedef unsigned short u16;
typedef unsigned char  u8;
typedef unsigned int   u32;

typedef short bf16x8 __attribute__((ext_vector_type(8)));
typedef float f32x4  __attribute__((ext_vector_type(4)));

#define DEV __device__ __forceinline__

DEV u16 f2bf(float x) {
  u32 u = __builtin_bit_cast(u32, x);
  u32 r = (u + 0x7fffu + ((u >> 16) & 1u)) >> 16;
  return (u16)r;
}
DEV float bf2f(u16 h) {
  u32 u = ((u32)h) << 16;
  return __builtin_bit_cast(float, u);
}
DEV f32x4 mfma16(bf16x8 a, bf16x8 b, f32x4 c) {
  return __builtin_amdgcn_mfma_f32_16x16x32_bf16(a, b, c, 0, 0, 0);
}

// ---------------------------------------------------------------------------
// 1) split fp32 -> bf16 hi/lo
// ---------------------------------------------------------------------------
__global__ __launch_bounds__(256) void split_kernel(
    const float* __restrict__ x, u16* __restrict__ hi, u16* __restrict__ lo, int n) {
  int i = blockIdx.x * 256 + threadIdx.x;
  if (i >= n) return;
  float v = x[i];
  u16 h = f2bf(v);
  hi[i] = h;
  lo[i] = f2bf(v - bf2f(h));
}

// ---------------------------------------------------------------------------
// 2) ca[h][k] = sum_j W[h*64+j][k] * a[j]   (fp64)
// ---------------------------------------------------------------------------
__global__ __launch_bounds__(256) void ca_kernel(
    const float* __restrict__ W, const float* __restrict__ ha, double* __restrict__ ca) {
  int idx = blockIdx.x * 256 + threadIdx.x;  // 16 * 1024
  int h = idx >> 10, k = idx & 1023;
  double s = 0.0;
#pragma unroll 8
  for (int j = 0; j < 64; ++j)
    s += (double)W[(size_t)(h * 64 + j) * 1024 + k] * (double)ha[j];
  ca[idx] = s;
}

// ---------------------------------------------------------------------------
// 3) d[bh][l] = sum_k hidden[row][k] * ca[h][k]   (fp64 acc; exact q-hash sign)
// ---------------------------------------------------------------------------
__global__ __launch_bounds__(256) void d_kernel(
    const float* __restrict__ hid, const double* __restrict__ ca, float* __restrict__ dq) {
  const int row  = blockIdx.x * 4 + (threadIdx.x >> 6);  // 0..4095
  const int lane = threadIdx.x & 63;
  const int b = row >> 11, l = row & 2047;
  double acc[16];
#pragma unroll
  for (int h = 0; h < 16; ++h) acc[h] = 0.0;
  const float* hp = hid + (size_t)row * 1024;
  for (int k = lane; k < 1024; k += 64) {
    const double hv = (double)hp[k];
#pragma unroll
    for (int h = 0; h < 16; ++h) acc[h] += hv * ca[h * 1024 + k];
  }
#pragma unroll
  for (int h = 0; h < 16; ++h) {
    double v = acc[h];
#pragma unroll
    for (int off = 32; off; off >>= 1) v += __shfl_xor(v, off, 64);
    if (lane == 0) dq[(size_t)(b * 16 + h) * 2048 + l] = (float)v;
  }
}

// ---------------------------------------------------------------------------
// 4) split-bf16 GEMM:  C[m][n] = sum_k A[m][k]*B[n][k] + bias[n]
// ---------------------------------------------------------------------------
template <int TERMS>
__global__ __launch_bounds__(256) void gemm_bt(
    const u16* __restrict__ Ahi, const u16* __restrict__ Alo,
    const u16* __restrict__ Bhi, const u16* __restrict__ Blo,
    const float* __restrict__ bias, float* __restrict__ Cf, u16* __restrict__ Cb) {
  constexpr int K = 1024, N = 1024;
  __shared__ u16 Ah[128 * 32];
  __shared__ u16 Bh[128 * 32];
  __shared__ u16 Al[TERMS > 1 ? 128 * 32 : 64];
  __shared__ u16 Bl[TERMS > 1 ? 128 * 32 : 64];
  const int tid = threadIdx.x;
  const int wave = tid >> 6, lane = tid & 63;
  const int quad = lane >> 4, lm = lane & 15;
  const int wr = wave >> 1, wc = wave & 1;
  const int m0 = blockIdx.x * 128, n0 = blockIdx.y * 128;

  f32x4 acc[4][4];
#pragma unroll
  for (int i = 0; i < 4; ++i)
#pragma unroll
    for (int j = 0; j < 4; ++j) acc[i][j] = {0.f, 0.f, 0.f, 0.f};

  for (int k0 = 0; k0 < K; k0 += 32) {
    __syncthreads();
#pragma unroll
    for (int it = 0; it < 2; ++it) {
      const int rb = wave * 2 + it;               // 16-row chunk id, wave-uniform
      const int row = rb * 16 + (lane >> 2);
      const int ch = lane & 3;
      const size_t goffA = (size_t)(m0 + row) * K + k0 + ch * 8;
      const size_t goffB = (size_t)(n0 + row) * K + k0 + ch * 8;
      __builtin_amdgcn_global_load_lds(
          (const __attribute__((address_space(1))) void*)(Ahi + goffA),
          (__attribute__((address_space(3))) void*)(Ah + rb * 512), 16, 0, 0);
      __builtin_amdgcn_global_load_lds(
          (const __attribute__((address_space(1))) void*)(Bhi + goffB),
          (__attribute__((address_space(3))) void*)(Bh + rb * 512), 16, 0, 0);
      if constexpr (TERMS > 1) {
        __builtin_amdgcn_global_load_lds(
            (const __attribute__((address_space(1))) void*)(Alo + goffA),
            (__attribute__((address_space(3))) void*)(Al + rb * 512), 16, 0, 0);
        __builtin_amdgcn_global_load_lds(
            (const __attribute__((address_space(1))) void*)(Blo + goffB),
            (__attribute__((address_space(3))) void*)(Bl + rb * 512), 16, 0, 0);
      }
    }
    __syncthreads();

    bf16x8 a_h[4], b_h[4], a_l[4], b_l[4];
#pragma unroll
    for (int i = 0; i < 4; ++i)
      a_h[i] = *(const bf16x8*)(Ah + (wr * 64 + i * 16 + lm) * 32 + quad * 8);
#pragma unroll
    for (int j = 0; j < 4; ++j)
      b_h[j] = *(const bf16x8*)(Bh + (wc * 64 + j * 16 + lm) * 32 + quad * 8);
    if constexpr (TERMS > 1) {
#pragma unroll
      for (int i = 0; i < 4; ++i)
        a_l[i] = *(const bf16x8*)(Al + (wr * 64 + i * 16 + lm) * 32 + quad * 8);
#pragma unroll
      for (int j = 0; j < 4; ++j)
        b_l[j] = *(const bf16x8*)(Bl + (wc * 64 + j * 16 + lm) * 32 + quad * 8);
    }
#pragma unroll
    for (int i = 0; i < 4; ++i)
#pragma unroll
      for (int j = 0; j < 4; ++j) {
        acc[i][j] = mfma16(a_h[i], b_h[j], acc[i][j]);
        if constexpr (TERMS > 1) {
          acc[i][j] = mfma16(a_h[i], b_l[j], acc[i][j]);
          acc[i][j] = mfma16(a_l[i], b_h[j], acc[i][j]);
        }
      }
  }

#pragma unroll
  for (int i = 0; i < 4; ++i)
#pragma unroll
    for (int j = 0; j < 4; ++j) {
      const int col = n0 + wc * 64 + j * 16 + lm;
      const float bv = bias[col];
#pragma unroll
      for (int r = 0; r < 4; ++r) {
        const int row = m0 + wr * 64 + i * 16 + quad * 4 + r;
        const float val = acc[i][j][r] + bv;
        const size_t idx = (size_t)row * N + col;
        if (Cf) Cf[idx] = val;
        Cb[idx] = f2bf(val);
      }
    }
}

// ---------------------------------------------------------------------------
// 4b) pre-transpose V: vB[b,l,h,d] -> vT[bh][d][key]  (64 x 2048 per bh)
// ---------------------------------------------------------------------------
__global__ __launch_bounds__(256) void vtrans_kernel(
    const u16* __restrict__ vB, u16* __restrict__ vT) {
  constexpr int TS = 72;
  __shared__ u16 Ts[64 * TS];
  const int kt = blockIdx.x, bh = blockIdx.y;
  const int b = bh >> 4, h = bh & 15;
  const int tid = threadIdx.x;
  const int row0 = tid >> 3, ch = tid & 7;
  const u16* src = vB + (size_t)b * 2048 * 1024 + h * 64;
#pragma unroll
  for (int it = 0; it < 2; ++it) {
    const int kr = row0 + it * 32;  // local key row
    uint4 v = *(const uint4*)(src + (size_t)(kt * 64 + kr) * 1024 + ch * 8);
    *(uint4*)((char*)Ts + kr * (TS * 2) + ch * 16) = v;
  }
  __syncthreads();
  u16* dst = vT + (size_t)bh * 64 * 2048 + kt * 64;
#pragma unroll
  for (int it = 0; it < 2; ++it) {
    const int d = row0 + it * 32;
    union { uint4 v; u16 s[8]; } u;
#pragma unroll
    for (int j = 0; j < 8; ++j) u.s[j] = Ts[(ch * 8 + j) * TS + d];
    *(uint4*)(dst + (size_t)d * 2048 + ch * 8) = u.v;
  }
}

// ---------------------------------------------------------------------------
// 5a) n2[bh][l]
// ---------------------------------------------------------------------------
__global__ __launch_bounds__(256) void norm_kernel(
    const float* __restrict__ qkF, float* __restrict__ n2A) {
  const int row = blockIdx.x;  // b*2048 + l
  const int tid = threadIdx.x;
  float4 v = ((const float4*)(qkF + (size_t)row * 1024))[tid];
  float s = v.x * v.x + v.y * v.y + v.z * v.z + v.w * v.w;
#pragma unroll
  for (int off = 1; off < 16; off <<= 1) s += __shfl_xor(s, off, 64);
  if ((tid & 15) == 0) {
    const int h = tid >> 4;
    const int b = row >> 11, l = row & 2047;
    n2A[(size_t)(b * 16 + h) * 2048 + l] = s;
  }
}

// ---------------------------------------------------------------------------
// 5b) hash bits per (b,h)
// ---------------------------------------------------------------------------
__global__ __launch_bounds__(256) void bits_kernel(
    const float* __restrict__ n2A, const float* __restrict__ dq,
    const float* __restrict__ ha, u8* __restrict__ hqA, u8* __restrict__ hkA) {
  const int bh = blockIdx.x;
  const int tid = threadIdx.x;
  const int wave = tid >> 6, lane = tid & 63;
  __shared__ float red[4];
  const float* n2p = n2A + (size_t)bh * 2048;
  float4 v0 = ((const float4*)n2p)[tid];
  float4 v1 = ((const float4*)n2p)[tid + 256];
  float lmax = fmaxf(fmaxf(fmaxf(v0.x, v0.y), fmaxf(v0.z, v0.w)),
                     fmaxf(fmaxf(v1.x, v1.y), fmaxf(v1.z, v1.w)));
#pragma unroll
  for (int off = 1; off < 64; off <<= 1) lmax = fmaxf(lmax, __shfl_xor(lmax, off, 64));
  if (lane == 0) red[wave] = lmax;
  __syncthreads();
  const float maxn2 = fmaxf(fmaxf(red[0], red[1]), fmaxf(red[2], red[3]));
  const float s = 0.75f / fmaxf(sqrtf(maxn2), 1e-12f);
  const float a64 = ha[64], a65 = ha[65];
#pragma unroll
  for (int it = 0; it < 8; ++it) {
    const int l = it * 256 + tid;
    const float dv = dq[(size_t)bh * 2048 + l];
    const float n2 = n2p[l];
    const float nk2 = s * s * n2;
    const float hkdot = s * dv + (0.5f - nk2) * a64 + (0.5f - nk2 * nk2) * a65;
    hqA[(size_t)bh * 2048 + l] = (dv >= 0.f) ? 1 : 0;
    hkA[(size_t)bh * 2048 + l] = (hkdot >= 0.f) ? 1 : 0;
  }
}

// ---------------------------------------------------------------------------
// 6) flash attention v2: V from vT (row-major staging), reg-prefetch K/V,
//    2 barriers/iter (Ps is per-wave -> no barrier), Q pre-scaled by 0.125.
// ---------------------------------------------------------------------------
__global__ __launch_bounds__(256) void attn_kernel(
    const u16* __restrict__ qkb, const u16* __restrict__ vT,
    const u8* __restrict__ hqA, const u8* __restrict__ hkA, float* __restrict__ out) {
  constexpr int STR = 72;
  const int qt = blockIdx.x;  // 0..31
  const int bh = blockIdx.y;  // 0..31
  const int b = bh >> 4, h = bh & 15;
  const int tid = threadIdx.x;
  const int wave = tid >> 6, lane = tid & 63;
  const int quad = lane >> 4, lm = lane & 15;

  __shared__ u16 Qs[64 * STR];
  __shared__ u16 Ks[64 * STR];
  __shared__ u16 Vs[64 * STR];  // [d][key]
  __shared__ u16 Ps[4][16 * STR];
  __shared__ u8 hqs[64];
  __shared__ u8 hks[64];

  const u16* qbase = qkb + (size_t)b * 2048 * 1024 + h * 64;
  const u16* vtbase = vT + (size_t)bh * 64 * 2048;
  const int q0 = qt * 64;
  const int row0 = tid >> 3, ch = tid & 7;

  // stage Q (pre-scaled by 1/sqrt(DH) = 0.125, exact in bf16)
  {
#pragma unroll
    for (int it = 0; it < 2; ++it) {
      const int row = row0 + it * 32;
      union { uint4 v; u16 s[8]; } u;
      u.v = *(const uint4*)(qbase + (size_t)(q0 + row) * 1024 + ch * 8);
#pragma unroll
      for (int j = 0; j < 8; ++j) u.s[j] = f2bf(bf2f(u.s[j]) * 0.125f);
      *(uint4*)((char*)Qs + row * (STR * 2) + ch * 16) = u.v;
    }
  }
  if (tid < 16)
    ((u32*)hqs)[tid] = ((const u32*)(hqA + (size_t)bh * 2048 + q0))[tid];

  // prefetch K/V tile 0 into registers
  uint4 kR0, kR1, vR0, vR1;
  u32 hkr = 0;
  kR0 = *(const uint4*)(qbase + (size_t)row0 * 1024 + ch * 8);
  kR1 = *(const uint4*)(qbase + (size_t)(row0 + 32) * 1024 + ch * 8);
  vR0 = *(const uint4*)(vtbase + (size_t)row0 * 2048 + ch * 8);
  vR1 = *(const uint4*)(vtbase + (size_t)(row0 + 32) * 2048 + ch * 8);
  if (tid < 16) hkr = ((const u32*)(hkA + (size_t)bh * 2048))[tid];

  __syncthreads();  // Qs/hqs ready

  bf16x8 aQ0 = *(const bf16x8*)(Qs + (wave * 16 + lm) * STR + quad * 8);
  bf16x8 aQ1 = *(const bf16x8*)(Qs + (wave * 16 + lm) * STR + 32 + quad * 8);
  u8 hqb[4];
#pragma unroll
  for (int r = 0; r < 4; ++r) hqb[r] = hqs[wave * 16 + quad * 4 + r];

  float m_i[4], l_i[4];
  f32x4 acc_o[4];
#pragma unroll
  for (int r = 0; r < 4; ++r) { m_i[r] = -1e30f; l_i[r] = 0.f; }
#pragma unroll
  for (int j = 0; j < 4; ++j) acc_o[j] = {0.f, 0.f, 0.f, 0.f};

  for (int kt = 0; kt < 32; ++kt) {
    __syncthreads();  // all waves done reading Ks/Vs of prev iter
    *(uint4*)((char*)Ks + row0 * (STR * 2) + ch * 16) = kR0;
    *(uint4*)((char*)Ks + (row0 + 32) * (STR * 2) + ch * 16) = kR1;
    *(uint4*)((char*)Vs + row0 * (STR * 2) + ch * 16) = vR0;
    *(uint4*)((char*)Vs + (row0 + 32) * (STR * 2) + ch * 16) = vR1;
    if (tid < 16) ((u32*)hks)[tid] = hkr;
    __syncthreads();  // tiles visible

    if (kt < 31) {  // prefetch next tile; latency overlaps compute below
      const int k0n = (kt + 1) * 64;
      kR0 = *(const uint4*)(qbase + (size_t)(k0n + row0) * 1024 + ch * 8);
      kR1 = *(const uint4*)(qbase + (size_t)(k0n + row0 + 32) * 1024 + ch * 8);
      vR0 = *(const uint4*)(vtbase + (size_t)row0 * 2048 + k0n + ch * 8);
      vR1 = *(const uint4*)(vtbase + (size_t)(row0 + 32) * 2048 + k0n + ch * 8);
      if (tid < 16) hkr = ((const u32*)(hkA + (size_t)bh * 2048 + k0n))[tid];
    }

    // S = (Q*0.125) K^T + mask
    float sv[4][4];
#pragma unroll
    for (int n = 0; n < 4; ++n) {
      bf16x8 b0 = *(const bf16x8*)(Ks + (n * 16 + lm) * STR + quad * 8);
      bf16x8 b1 = *(const bf16x8*)(Ks + (n * 16 + lm) * STR + 32 + quad * 8);
      f32x4 c = {0.f, 0.f, 0.f, 0.f};
      c = mfma16(aQ0, b0, c);
      c = mfma16(aQ1, b1, c);
      const u8 hkb = hks[n * 16 + lm];
#pragma unroll
      for (int r = 0; r < 4; ++r)
        sv[n][r] = c[r] + ((hqb[r] == hkb) ? 0.f : -1e4f);
    }
    // online softmax
    float alpha[4], rsum[4];
#pragma unroll
    for (int r = 0; r < 4; ++r) {
      float mx = fmaxf(fmaxf(sv[0][r], sv[1][r]), fmaxf(sv[2][r], sv[3][r]));
#pragma unroll
      for (int off = 1; off < 16; off <<= 1) mx = fmaxf(mx, __shfl_xor(mx, off, 64));
      const float mn = fmaxf(m_i[r], mx);
      alpha[r] = __expf(m_i[r] - mn);
      m_i[r] = mn;
      rsum[r] = 0.f;
    }
#pragma unroll
    for (int n = 0; n < 4; ++n)
#pragma unroll
      for (int r = 0; r < 4; ++r) {
        const float p = __expf(sv[n][r] - m_i[r]);
        rsum[r] += p;
        Ps[wave][(quad * 4 + r) * STR + n * 16 + lm] = f2bf(p);
      }
#pragma unroll
    for (int r = 0; r < 4; ++r) {
      float s = rsum[r];
#pragma unroll
      for (int off = 1; off < 16; off <<= 1) s += __shfl_xor(s, off, 64);
      l_i[r] = l_i[r] * alpha[r] + s;
    }
#pragma unroll
    for (int j = 0; j < 4; ++j)
#pragma unroll
      for (int r = 0; r < 4; ++r) acc_o[j][r] *= alpha[r];

    // Ps round-trip is same-wave only: lgkmcnt ordering suffices, no barrier
    bf16x8 aP0 = *(const bf16x8*)(&Ps[wave][lm * STR + quad * 8]);
    bf16x8 aP1 = *(const bf16x8*)(&Ps[wave][lm * STR + 32 + quad * 8]);
#pragma unroll
    for (int j = 0; j < 4; ++j) {
      bf16x8 v0 = *(const bf16x8*)(Vs + (j * 16 + lm) * STR + quad * 8);
      bf16x8 v1 = *(const bf16x8*)(Vs + (j * 16 + lm) * STR + 32 + quad * 8);
      acc_o[j] = mfma16(aP0, v0, acc_o[j]);
      acc_o[j] = mfma16(aP1, v1, acc_o[j]);
    }
  }

#pragma unroll
  for (int r = 0; r < 4; ++r) {
    const float inv = 1.0f / l_i[r];
    const int row = q0 + wave * 16 + quad * 4 + r;
    float* op = out + (size_t)(b * 2048 + row) * 1024 + h * 64;
#pragma unroll
    for (int j = 0; j < 4; ++j) op[j * 16 + lm] = acc_o[j][r] * inv;
  }
}

// ---------------------------------------------------------------------------
extern "C" void kernel_launch(void* const* d_in, const int* in_sizes, int n_in,
                              void* d_out, int out_size, void* d_ws, size_t ws_size,
                              hipStream_t stream) {
  const float* hidden = (const float*)d_in[0];
  const float* qk_w   = (const float*)d_in[1];
  const float* qk_b   = (const float*)d_in[2];
  const float* v_w    = (const float*)d_in[3];
  const float* v_b    = (const float*)d_in[4];
  const float* hash_a = (const float*)d_in[5];
  float* out = (float*)d_out;

  char* base = (char*)d_ws;
  size_t off = 0;
  auto take = [&](size_t bytes) -> char* {
    char* r = base + off;
    off += (bytes + 255) & ~(size_t)255;
    return r;
  };
  const size_t NH = 4194304;  // B*L*D
  const size_t NW = 1048576;  // D*D
  u16* hHi  = (u16*)take(NH * 2);
  u16* hLo  = (u16*)take(NH * 2);
  u16* wqHi = (u16*)take(NW * 2);
  u16* wqLo = (u16*)take(NW * 2);
  u16* wvHi = (u16*)take(NW * 2);
  u16* wvLo = (u16*)take(NW * 2);
  float* qkF = (float*)take(NH * 4);
  u16* qkB  = (u16*)take(NH * 2);
  u16* vB   = (u16*)take(NH * 2);
  u16* vT   = (u16*)take(NH * 2);
  double* ca = (double*)take(16 * 1024 * 8);
  float* dq  = (float*)take(65536 * 4);
  float* n2A = (float*)take(65536 * 4);
  u8* hqA = (u8*)take(65536);
  u8* hkA = (u8*)take(65536);

  hipLaunchKernelGGL(split_kernel, dim3(NH / 256), dim3(256), 0, stream, hidden, hHi, hLo, (int)NH);
  hipLaunchKernelGGL(split_kernel, dim3(NW / 256), dim3(256), 0, stream, qk_w, wqHi, wqLo, (int)NW);
  hipLaunchKernelGGL(split_kernel, dim3(NW / 256), dim3(256), 0, stream, v_w, wvHi, wvLo, (int)NW);
  hipLaunchKernelGGL(ca_kernel, dim3(64), dim3(256), 0, stream, qk_w, hash_a, ca);
  hipLaunchKernelGGL(d_kernel, dim3(1024), dim3(256), 0, stream, hidden, ca, dq);
  hipLaunchKernelGGL((gemm_bt<3>), dim3(32, 8), dim3(256), 0, stream, hHi, hLo, wqHi, wqLo, qk_b, qkF, qkB);
  hipLaunchKernelGGL((gemm_bt<1>), dim3(32, 8), dim3(256), 0, stream, hHi, (const u16*)nullptr, wvHi,
                     (const u16*)nullptr, v_b, (float*)nullptr, vB);
  hipLaunchKernelGGL(vtrans_kernel, dim3(32, 32), dim3(256), 0, stream, vB, vT);
  hipLaunchKernelGGL(norm_kernel, dim3(4096), dim3(256), 0, stream, qkF, n2A);
  hipLaunchKernelGGL(bits_kernel, dim3(32), dim3(256), 0, stream, n2A, dq, hash_a, hqA, hkA);
  hipLaunchKernelGGL(attn_kernel, dim3(32, 32), dim3(256), 0, stream, qkB, vT, hqA, hkA, out);
}

// Round 4
// 280.352 us; speedup vs baseline: 2.2675x; 1.1599x over previous
//
#include <hip/hip_runtime.h>

typedef unsigned short u16;
typedef unsigned char  u8;
typedef unsigned int   u32;

typedef short bf16x8 __attribute__((ext_vector_type(8)));
typedef float f32x4  __attribute__((ext_vector_type(4)));

#define DEV __device__ __forceinline__

#if __has_builtin(__builtin_amdgcn_exp2f)
#define EXP2(x) __builtin_amdgcn_exp2f(x)
#else
#define EXP2(x) exp2f(x)
#endif

DEV u16 f2bf(float x) {
  u32 u = __builtin_bit_cast(u32, x);
  u32 r = (u + 0x7fffu + ((u >> 16) & 1u)) >> 16;
  return (u16)r;
}
DEV float bf2f(u16 h) {
  u32 u = ((u32)h) << 16;
  return __builtin_bit_cast(float, u);
}
DEV f32x4 mfma16(bf16x8 a, bf16x8 b, f32x4 c) {
  return __builtin_amdgcn_mfma_f32_16x16x32_bf16(a, b, c, 0, 0, 0);
}

// ---------------------------------------------------------------------------
// 1) split fp32 -> bf16 hi/lo
// ---------------------------------------------------------------------------
__global__ __launch_bounds__(256) void split_kernel(
    const float* __restrict__ x, u16* __restrict__ hi, u16* __restrict__ lo, int n) {
  int i = blockIdx.x * 256 + threadIdx.x;
  if (i >= n) return;
  float v = x[i];
  u16 h = f2bf(v);
  hi[i] = h;
  lo[i] = f2bf(v - bf2f(h));
}

// ---------------------------------------------------------------------------
// 2) ca[h][k] = sum_j W[h*64+j][k] * a[j]   (fp64)
// ---------------------------------------------------------------------------
__global__ __launch_bounds__(256) void ca_kernel(
    const float* __restrict__ W, const float* __restrict__ ha, double* __restrict__ ca) {
  int idx = blockIdx.x * 256 + threadIdx.x;  // 16 * 1024
  int h = idx >> 10, k = idx & 1023;
  double s = 0.0;
#pragma unroll 8
  for (int j = 0; j < 64; ++j)
    s += (double)W[(size_t)(h * 64 + j) * 1024 + k] * (double)ha[j];
  ca[idx] = s;
}

// ---------------------------------------------------------------------------
// 3) d[bh][l] = sum_k hidden[row][k] * ca[h][k]   (fp64 acc; exact q-hash sign)
// ---------------------------------------------------------------------------
__global__ __launch_bounds__(256) void d_kernel(
    const float* __restrict__ hid, const double* __restrict__ ca, float* __restrict__ dq) {
  const int row  = blockIdx.x * 4 + (threadIdx.x >> 6);  // 0..4095
  const int lane = threadIdx.x & 63;
  const int b = row >> 11, l = row & 2047;
  double acc[16];
#pragma unroll
  for (int h = 0; h < 16; ++h) acc[h] = 0.0;
  const float* hp = hid + (size_t)row * 1024;
  for (int k = lane; k < 1024; k += 64) {
    const double hv = (double)hp[k];
#pragma unroll
    for (int h = 0; h < 16; ++h) acc[h] += hv * ca[h * 1024 + k];
  }
#pragma unroll
  for (int h = 0; h < 16; ++h) {
    double v = acc[h];
#pragma unroll
    for (int off = 32; off; off >>= 1) v += __shfl_xor(v, off, 64);
    if (lane == 0) dq[(size_t)(b * 16 + h) * 2048 + l] = (float)v;
  }
}

// ---------------------------------------------------------------------------
// 4) split-bf16 GEMM:  C[m][n] = sum_k A[m][k]*B[n][k] + bias[n]
// ---------------------------------------------------------------------------
template <int TERMS>
__global__ __launch_bounds__(256) void gemm_bt(
    const u16* __restrict__ Ahi, const u16* __restrict__ Alo,
    const u16* __restrict__ Bhi, const u16* __restrict__ Blo,
    const float* __restrict__ bias, float* __restrict__ Cf, u16* __restrict__ Cb) {
  constexpr int K = 1024, N = 1024;
  __shared__ u16 Ah[128 * 32];
  __shared__ u16 Bh[128 * 32];
  __shared__ u16 Al[TERMS > 1 ? 128 * 32 : 64];
  __shared__ u16 Bl[TERMS > 1 ? 128 * 32 : 64];
  const int tid = threadIdx.x;
  const int wave = tid >> 6, lane = tid & 63;
  const int quad = lane >> 4, lm = lane & 15;
  const int wr = wave >> 1, wc = wave & 1;
  const int m0 = blockIdx.x * 128, n0 = blockIdx.y * 128;

  f32x4 acc[4][4];
#pragma unroll
  for (int i = 0; i < 4; ++i)
#pragma unroll
    for (int j = 0; j < 4; ++j) acc[i][j] = {0.f, 0.f, 0.f, 0.f};

  for (int k0 = 0; k0 < K; k0 += 32) {
    __syncthreads();
#pragma unroll
    for (int it = 0; it < 2; ++it) {
      const int rb = wave * 2 + it;               // 16-row chunk id, wave-uniform
      const int row = rb * 16 + (lane >> 2);
      const int ch = lane & 3;
      const size_t goffA = (size_t)(m0 + row) * K + k0 + ch * 8;
      const size_t goffB = (size_t)(n0 + row) * K + k0 + ch * 8;
      __builtin_amdgcn_global_load_lds(
          (const __attribute__((address_space(1))) void*)(Ahi + goffA),
          (__attribute__((address_space(3))) void*)(Ah + rb * 512), 16, 0, 0);
      __builtin_amdgcn_global_load_lds(
          (const __attribute__((address_space(1))) void*)(Bhi + goffB),
          (__attribute__((address_space(3))) void*)(Bh + rb * 512), 16, 0, 0);
      if constexpr (TERMS > 1) {
        __builtin_amdgcn_global_load_lds(
            (const __attribute__((address_space(1))) void*)(Alo + goffA),
            (__attribute__((address_space(3))) void*)(Al + rb * 512), 16, 0, 0);
        __builtin_amdgcn_global_load_lds(
            (const __attribute__((address_space(1))) void*)(Blo + goffB),
            (__attribute__((address_space(3))) void*)(Bl + rb * 512), 16, 0, 0);
      }
    }
    __syncthreads();

    bf16x8 a_h[4], b_h[4], a_l[4], b_l[4];
#pragma unroll
    for (int i = 0; i < 4; ++i)
      a_h[i] = *(const bf16x8*)(Ah + (wr * 64 + i * 16 + lm) * 32 + quad * 8);
#pragma unroll
    for (int j = 0; j < 4; ++j)
      b_h[j] = *(const bf16x8*)(Bh + (wc * 64 + j * 16 + lm) * 32 + quad * 8);
    if constexpr (TERMS > 1) {
#pragma unroll
      for (int i = 0; i < 4; ++i)
        a_l[i] = *(const bf16x8*)(Al + (wr * 64 + i * 16 + lm) * 32 + quad * 8);
#pragma unroll
      for (int j = 0; j < 4; ++j)
        b_l[j] = *(const bf16x8*)(Bl + (wc * 64 + j * 16 + lm) * 32 + quad * 8);
    }
#pragma unroll
    for (int i = 0; i < 4; ++i)
#pragma unroll
      for (int j = 0; j < 4; ++j) {
        acc[i][j] = mfma16(a_h[i], b_h[j], acc[i][j]);
        if constexpr (TERMS > 1) {
          acc[i][j] = mfma16(a_h[i], b_l[j], acc[i][j]);
          acc[i][j] = mfma16(a_l[i], b_h[j], acc[i][j]);
        }
      }
  }

#pragma unroll
  for (int i = 0; i < 4; ++i)
#pragma unroll
    for (int j = 0; j < 4; ++j) {
      const int col = n0 + wc * 64 + j * 16 + lm;
      const float bv = bias[col];
#pragma unroll
      for (int r = 0; r < 4; ++r) {
        const int row = m0 + wr * 64 + i * 16 + quad * 4 + r;
        const float val = acc[i][j][r] + bv;
        const size_t idx = (size_t)row * N + col;
        if (Cf) Cf[idx] = val;
        Cb[idx] = f2bf(val);
      }
    }
}

// ---------------------------------------------------------------------------
// 4b) pre-transpose V: vB[b,l,h,d] -> vT[bh][d][key]  (64 x 2048 per bh)
// ---------------------------------------------------------------------------
__global__ __launch_bounds__(256) void vtrans_kernel(
    const u16* __restrict__ vB, u16* __restrict__ vT) {
  constexpr int TS = 72;
  __shared__ u16 Ts[64 * TS];
  const int kt = blockIdx.x, bh = blockIdx.y;
  const int b = bh >> 4, h = bh & 15;
  const int tid = threadIdx.x;
  const int row0 = tid >> 3, ch = tid & 7;
  const u16* src = vB + (size_t)b * 2048 * 1024 + h * 64;
#pragma unroll
  for (int it = 0; it < 2; ++it) {
    const int kr = row0 + it * 32;  // local key row
    uint4 v = *(const uint4*)(src + (size_t)(kt * 64 + kr) * 1024 + ch * 8);
    *(uint4*)((char*)Ts + kr * (TS * 2) + ch * 16) = v;
  }
  __syncthreads();
  u16* dst = vT + (size_t)bh * 64 * 2048 + kt * 64;
#pragma unroll
  for (int it = 0; it < 2; ++it) {
    const int d = row0 + it * 32;
    union { uint4 v; u16 s[8]; } u;
#pragma unroll
    for (int j = 0; j < 8; ++j) u.s[j] = Ts[(ch * 8 + j) * TS + d];
    *(uint4*)(dst + (size_t)d * 2048 + ch * 8) = u.v;
  }
}

// ---------------------------------------------------------------------------
// 5a) n2[bh][l]
// ---------------------------------------------------------------------------
__global__ __launch_bounds__(256) void norm_kernel(
    const float* __restrict__ qkF, float* __restrict__ n2A) {
  const int row = blockIdx.x;  // b*2048 + l
  const int tid = threadIdx.x;
  float4 v = ((const float4*)(qkF + (size_t)row * 1024))[tid];
  float s = v.x * v.x + v.y * v.y + v.z * v.z + v.w * v.w;
#pragma unroll
  for (int off = 1; off < 16; off <<= 1) s += __shfl_xor(s, off, 64);
  if ((tid & 15) == 0) {
    const int h = tid >> 4;
    const int b = row >> 11, l = row & 2047;
    n2A[(size_t)(b * 16 + h) * 2048 + l] = s;
  }
}

// ---------------------------------------------------------------------------
// 5b) hash bits per (b,h)
// ---------------------------------------------------------------------------
__global__ __launch_bounds__(256) void bits_kernel(
    const float* __restrict__ n2A, const float* __restrict__ dq,
    const float* __restrict__ ha, u8* __restrict__ hqA, u8* __restrict__ hkA) {
  const int bh = blockIdx.x;
  const int tid = threadIdx.x;
  const int wave = tid >> 6, lane = tid & 63;
  __shared__ float red[4];
  const float* n2p = n2A + (size_t)bh * 2048;
  float4 v0 = ((const float4*)n2p)[tid];
  float4 v1 = ((const float4*)n2p)[tid + 256];
  float lmax = fmaxf(fmaxf(fmaxf(v0.x, v0.y), fmaxf(v0.z, v0.w)),
                     fmaxf(fmaxf(v1.x, v1.y), fmaxf(v1.z, v1.w)));
#pragma unroll
  for (int off = 1; off < 64; off <<= 1) lmax = fmaxf(lmax, __shfl_xor(lmax, off, 64));
  if (lane == 0) red[wave] = lmax;
  __syncthreads();
  const float maxn2 = fmaxf(fmaxf(red[0], red[1]), fmaxf(red[2], red[3]));
  const float s = 0.75f / fmaxf(sqrtf(maxn2), 1e-12f);
  const float a64 = ha[64], a65 = ha[65];
#pragma unroll
  for (int it = 0; it < 8; ++it) {
    const int l = it * 256 + tid;
    const float dv = dq[(size_t)bh * 2048 + l];
    const float n2 = n2p[l];
    const float nk2 = s * s * n2;
    const float hkdot = s * dv + (0.5f - nk2) * a64 + (0.5f - nk2 * nk2) * a65;
    hqA[(size_t)bh * 2048 + l] = (dv >= 0.f) ? 1 : 0;
    hkA[(size_t)bh * 2048 + l] = (hkdot >= 0.f) ? 1 : 0;
  }
}

// ---------------------------------------------------------------------------
// 6) flash attention v3: fixed-C softmax (no online rescale, no shuffles),
//    128 q/block (32/wave), global_load_lds dbuf staging w/ XOR swizzle,
//    1 barrier/iter, l via MFMA-with-ones, scale folded into exp2 argument.
// ---------------------------------------------------------------------------
__global__ __launch_bounds__(256, 3) void attn_kernel(
    const u16* __restrict__ qkb, const u16* __restrict__ vT,
    const u8* __restrict__ hqA, const u8* __restrict__ hkA, float* __restrict__ out) {
  __shared__ u16 Ks[2][4096];   // [buf][key(64) x dim(64)], 16B-chunk XOR swizzle
  __shared__ u16 Vs[2][4096];   // [buf][dim(64) x key(64)], same swizzle
  __shared__ u16 Ps[4][2048];   // [wave][qrow(32) x key(64)], same swizzle

  const int qt = blockIdx.x;    // 0..15 (128 queries each)
  const int bh = blockIdx.y;    // 0..31
  const int b = bh >> 4, h = bh & 15;
  const int tid = threadIdx.x, wave = tid >> 6, lane = tid & 63;
  const int quad = lane >> 4, lm = lane & 15;
  const int lx = lm & 7;
  const int r8 = lane >> 3, ch = lane & 7;
  const int q0 = qt * 128;

  const u16* qbase = qkb + (size_t)b * 2048 * 1024 + h * 64;
  const u16* vtb = vT + (size_t)bh * 64 * 2048;
  const u8* hkp = hkA + (size_t)bh * 2048;

  // Q A-frags straight from global (raw; 1/sqrt(DH) folded into exp2 arg)
  bf16x8 aQ[2][2];
#pragma unroll
  for (int s = 0; s < 2; ++s)
#pragma unroll
    for (int c = 0; c < 2; ++c)
      aQ[s][c] = *(const bf16x8*)(qbase +
          (size_t)(q0 + wave * 32 + s * 16 + lm) * 1024 + c * 32 + quad * 8);
  u8 hqb[2][4];
  {
    const u8* hqp = hqA + (size_t)bh * 2048 + q0 + wave * 32;
#pragma unroll
    for (int s = 0; s < 2; ++s)
#pragma unroll
      for (int r = 0; r < 4; ++r) hqb[s][r] = hqp[s * 16 + quad * 4 + r];
  }

  const int srow = wave * 16;  // this wave's 16-row staging slab
  auto stage = [&](int kt, int buf) {
#pragma unroll
    for (int i = 0; i < 2; ++i) {
      const int row = srow + i * 8 + r8;  // key row for K / dim row for V
      const int sw = (ch ^ (row & 7)) * 8;
      __builtin_amdgcn_global_load_lds(
          (const __attribute__((address_space(1))) void*)(
              qbase + (size_t)(kt * 64 + row) * 1024 + sw),
          (__attribute__((address_space(3))) void*)(&Ks[buf][(srow + i * 8) * 64]),
          16, 0, 0);
      __builtin_amdgcn_global_load_lds(
          (const __attribute__((address_space(1))) void*)(
              vtb + (size_t)row * 2048 + kt * 64 + sw),
          (__attribute__((address_space(3))) void*)(&Vs[buf][(srow + i * 8) * 64]),
          16, 0, 0);
    }
  };

  stage(0, 0);

  f32x4 acc_o[2][4], accL[2];
#pragma unroll
  for (int s = 0; s < 2; ++s) {
    accL[s] = {0.f, 0.f, 0.f, 0.f};
#pragma unroll
    for (int j = 0; j < 4; ++j) acc_o[s][j] = {0.f, 0.f, 0.f, 0.f};
  }
  const bf16x8 ones = {0x3F80, 0x3F80, 0x3F80, 0x3F80, 0x3F80, 0x3F80, 0x3F80, 0x3F80};
  const float SCL = 0.18033688f;        // 0.125 * log2(e)
  const float M0 = -4.3280854f;         // -C*log2(e), C = 3
  const float M1 = -1.4430768e4f;       // -(1e4 + C)*log2(e)  -> exp2 underflows to 0

  __syncthreads();  // tile 0 staged (barrier drains vmcnt)

  for (int kt = 0; kt < 32; ++kt) {
    const int cur = kt & 1;
    if (kt < 31) stage(kt + 1, cur ^ 1);

    u8 hkv[4];
#pragma unroll
    for (int nb = 0; nb < 4; ++nb) hkv[nb] = hkp[kt * 64 + nb * 16 + lm];

    // S = Q K^T (raw dot products; scaling folded into exp)
    f32x4 cs[2][4];
#pragma unroll
    for (int s = 0; s < 2; ++s)
#pragma unroll
      for (int nb = 0; nb < 4; ++nb) cs[s][nb] = {0.f, 0.f, 0.f, 0.f};
#pragma unroll
    for (int c = 0; c < 2; ++c)
#pragma unroll
      for (int nb = 0; nb < 4; ++nb) {
        bf16x8 bK = *(const bf16x8*)&Ks[cur][(nb * 16 + lm) * 64 + (((c * 4 + quad) ^ lx) * 8)];
        cs[0][nb] = mfma16(aQ[0][c], bK, cs[0][nb]);
        cs[1][nb] = mfma16(aQ[1][c], bK, cs[1][nb]);
      }

    // p = 2^(s*SCL + msel); write bf16 (truncation) into swizzled Ps
#pragma unroll
    for (int s = 0; s < 2; ++s)
#pragma unroll
      for (int nb = 0; nb < 4; ++nb)
#pragma unroll
        for (int r = 0; r < 4; ++r) {
          const float msel = (hqb[s][r] == hkv[nb]) ? M0 : M1;
          const float p = EXP2(__builtin_fmaf(cs[s][nb][r], SCL, msel));
          const int prow = s * 16 + quad * 4 + r;
          const int pc = (nb * 2 + (lm >> 3)) ^ (prow & 7);
          union { float f; u16 hw[2]; } u;
          u.f = p;
          Ps[wave][prow * 64 + pc * 8 + lx] = u.hw[1];
        }

    // P frags (same-wave round trip; lgkm ordering, no barrier) + l via ones-MFMA
    bf16x8 aP[2][2];
#pragma unroll
    for (int s = 0; s < 2; ++s)
#pragma unroll
      for (int c = 0; c < 2; ++c) {
        aP[s][c] = *(const bf16x8*)&Ps[wave][(s * 16 + lm) * 64 + (((c * 4 + quad) ^ lx) * 8)];
        accL[s] = mfma16(aP[s][c], ones, accL[s]);
      }
    // O += P V
#pragma unroll
    for (int c = 0; c < 2; ++c)
#pragma unroll
      for (int j = 0; j < 4; ++j) {
        bf16x8 bV = *(const bf16x8*)&Vs[cur][(j * 16 + lm) * 64 + (((c * 4 + quad) ^ lx) * 8)];
        acc_o[0][j] = mfma16(aP[0][c], bV, acc_o[0][j]);
        acc_o[1][j] = mfma16(aP[1][c], bV, acc_o[1][j]);
      }

    __syncthreads();  // prev-tile reads done + next-tile staging drained
  }

#pragma unroll
  for (int s = 0; s < 2; ++s)
#pragma unroll
    for (int r = 0; r < 4; ++r) {
      const float inv = 1.0f / accL[s][r];
      float* op = out + (size_t)(b * 2048 + q0 + wave * 32 + s * 16 + quad * 4 + r) * 1024 + h * 64;
#pragma unroll
      for (int j = 0; j < 4; ++j) op[j * 16 + lm] = acc_o[s][j][r] * inv;
    }
}

// ---------------------------------------------------------------------------
extern "C" void kernel_launch(void* const* d_in, const int* in_sizes, int n_in,
                              void* d_out, int out_size, void* d_ws, size_t ws_size,
                              hipStream_t stream) {
  const float* hidden = (const float*)d_in[0];
  const float* qk_w   = (const float*)d_in[1];
  const float* qk_b   = (const float*)d_in[2];
  const float* v_w    = (const float*)d_in[3];
  const float* v_b    = (const float*)d_in[4];
  const float* hash_a = (const float*)d_in[5];
  float* out = (float*)d_out;

  char* base = (char*)d_ws;
  size_t off = 0;
  auto take = [&](size_t bytes) -> char* {
    char* r = base + off;
    off += (bytes + 255) & ~(size_t)255;
    return r;
  };
  const size_t NH = 4194304;  // B*L*D
  const size_t NW = 1048576;  // D*D
  u16* hHi  = (u16*)take(NH * 2);
  u16* hLo  = (u16*)take(NH * 2);
  u16* wqHi = (u16*)take(NW * 2);
  u16* wqLo = (u16*)take(NW * 2);
  u16* wvHi = (u16*)take(NW * 2);
  u16* wvLo = (u16*)take(NW * 2);
  float* qkF = (float*)take(NH * 4);
  u16* qkB  = (u16*)take(NH * 2);
  u16* vB   = (u16*)take(NH * 2);
  u16* vT   = (u16*)take(NH * 2);
  double* ca = (double*)take(16 * 1024 * 8);
  float* dq  = (float*)take(65536 * 4);
  float* n2A = (float*)take(65536 * 4);
  u8* hqA = (u8*)take(65536);
  u8* hkA = (u8*)take(65536);

  hipLaunchKernelGGL(split_kernel, dim3(NH / 256), dim3(256), 0, stream, hidden, hHi, hLo, (int)NH);
  hipLaunchKernelGGL(split_kernel, dim3(NW / 256), dim3(256), 0, stream, qk_w, wqHi, wqLo, (int)NW);
  hipLaunchKernelGGL(split_kernel, dim3(NW / 256), dim3(256), 0, stream, v_w, wvHi, wvLo, (int)NW);
  hipLaunchKernelGGL(ca_kernel, dim3(64), dim3(256), 0, stream, qk_w, hash_a, ca);
  hipLaunchKernelGGL(d_kernel, dim3(1024), dim3(256), 0, stream, hidden, ca, dq);
  hipLaunchKernelGGL((gemm_bt<3>), dim3(32, 8), dim3(256), 0, stream, hHi, hLo, wqHi, wqLo, qk_b, qkF, qkB);
  hipLaunchKernelGGL((gemm_bt<1>), dim3(32, 8), dim3(256), 0, stream, hHi, (const u16*)nullptr, wvHi,
                     (const u16*)nullptr, v_b, (float*)nullptr, vB);
  hipLaunchKernelGGL(vtrans_kernel, dim3(32, 32), dim3(256), 0, stream, vB, vT);
  hipLaunchKernelGGL(norm_kernel, dim3(4096), dim3(256), 0, stream, qkF, n2A);
  hipLaunchKernelGGL(bits_kernel, dim3(32), dim3(256), 0, stream, n2A, dq, hash_a, hqA, hkA);
  hipLaunchKernelGGL(attn_kernel, dim3(16, 32), dim3(256), 0, stream, qkB, vT, hqA, hkA, out);
}

// Round 5
// 257.030 us; speedup vs baseline: 2.4732x; 1.0907x over previous
//
#include <hip/hip_runtime.h>

typedef unsigned short u16;
typedef unsigned char  u8;
typedef unsigned int   u32;

typedef short bf16x8 __attribute__((ext_vector_type(8)));
typedef float f32x4  __attribute__((ext_vector_type(4)));

#define DEV __device__ __forceinline__

#if __has_builtin(__builtin_amdgcn_exp2f)
#define EXP2(x) __builtin_amdgcn_exp2f(x)
#else
#define EXP2(x) exp2f(x)
#endif

DEV u16 f2bf(float x) {
  u32 u = __builtin_bit_cast(u32, x);
  u32 r = (u + 0x7fffu + ((u >> 16) & 1u)) >> 16;
  return (u16)r;
}
DEV float bf2f(u16 h) {
  u32 u = ((u32)h) << 16;
  return __builtin_bit_cast(float, u);
}
DEV f32x4 mfma16(bf16x8 a, bf16x8 b, f32x4 c) {
  return __builtin_amdgcn_mfma_f32_16x16x32_bf16(a, b, c, 0, 0, 0);
}

// ---------------------------------------------------------------------------
// 1) split fp32 -> bf16 hi/lo
// ---------------------------------------------------------------------------
__global__ __launch_bounds__(256) void split_kernel(
    const float* __restrict__ x, u16* __restrict__ hi, u16* __restrict__ lo, int n) {
  int i = blockIdx.x * 256 + threadIdx.x;
  if (i >= n) return;
  float v = x[i];
  u16 h = f2bf(v);
  hi[i] = h;
  lo[i] = f2bf(v - bf2f(h));
}

// ---------------------------------------------------------------------------
// 2) ca[h][k] = sum_j W[h*64+j][k] * a[j]   (fp64)
// ---------------------------------------------------------------------------
__global__ __launch_bounds__(256) void ca_kernel(
    const float* __restrict__ W, const float* __restrict__ ha, double* __restrict__ ca) {
  int idx = blockIdx.x * 256 + threadIdx.x;  // 16 * 1024
  int h = idx >> 10, k = idx & 1023;
  double s = 0.0;
#pragma unroll 8
  for (int j = 0; j < 64; ++j)
    s += (double)W[(size_t)(h * 64 + j) * 1024 + k] * (double)ha[j];
  ca[idx] = s;
}

// ---------------------------------------------------------------------------
// 3) d[bh][l] = sum_k hidden[row][k] * ca[h][k]   (fp64 acc; exact q-hash sign)
// ---------------------------------------------------------------------------
__global__ __launch_bounds__(256) void d_kernel(
    const float* __restrict__ hid, const double* __restrict__ ca, float* __restrict__ dq) {
  const int row  = blockIdx.x * 4 + (threadIdx.x >> 6);  // 0..4095
  const int lane = threadIdx.x & 63;
  const int b = row >> 11, l = row & 2047;
  double acc[16];
#pragma unroll
  for (int h = 0; h < 16; ++h) acc[h] = 0.0;
  const float* hp = hid + (size_t)row * 1024;
  for (int k = lane; k < 1024; k += 64) {
    const double hv = (double)hp[k];
#pragma unroll
    for (int h = 0; h < 16; ++h) acc[h] += hv * ca[h * 1024 + k];
  }
#pragma unroll
  for (int h = 0; h < 16; ++h) {
    double v = acc[h];
#pragma unroll
    for (int off = 32; off; off >>= 1) v += __shfl_xor(v, off, 64);
    if (lane == 0) dq[(size_t)(b * 16 + h) * 2048 + l] = (float)v;
  }
}

// ---------------------------------------------------------------------------
// 4) fused dual GEMM, grid (32,8,2):
//    z=0: qk = hidden @ qk_w^T + qk_b   (3-term split-bf16, fp32-grade)
//         -> qkB (bf16) + n2A (per-head row sumsq, fused epilogue)
//    z=1: v  = hidden @ v_w^T + v_b    (1-term bf16)  -> vB
//    512 blocks = 2/CU so the two GEMMs' barrier stalls overlap.
// ---------------------------------------------------------------------------
__global__ __launch_bounds__(256) void gemm_fused(
    const u16* __restrict__ hHi, const u16* __restrict__ hLo,
    const u16* __restrict__ wqHi, const u16* __restrict__ wqLo,
    const u16* __restrict__ wvHi,
    const float* __restrict__ qk_b, const float* __restrict__ v_b,
    u16* __restrict__ qkB, u16* __restrict__ vB, float* __restrict__ n2A) {
  constexpr int K = 1024, N = 1024;
  __shared__ u16 Ah[128 * 32];
  __shared__ u16 Bh[128 * 32];
  __shared__ u16 Al[128 * 32];
  __shared__ u16 Bl[128 * 32];

  const int zsel = blockIdx.z;
  const u16* __restrict__ Ahi = hHi;
  const u16* __restrict__ Bhi = zsel ? wvHi : wqHi;
  const float* __restrict__ bias = zsel ? v_b : qk_b;
  u16* __restrict__ Cb = zsel ? vB : qkB;
  const int terms = zsel ? 1 : 3;

  const int tid = threadIdx.x;
  const int wave = tid >> 6, lane = tid & 63;
  const int quad = lane >> 4, lm = lane & 15;
  const int wr = wave >> 1, wc = wave & 1;
  const int m0 = blockIdx.x * 128, n0 = blockIdx.y * 128;

  f32x4 acc[4][4];
#pragma unroll
  for (int i = 0; i < 4; ++i)
#pragma unroll
    for (int j = 0; j < 4; ++j) acc[i][j] = {0.f, 0.f, 0.f, 0.f};

  for (int k0 = 0; k0 < K; k0 += 32) {
    __syncthreads();
#pragma unroll
    for (int it = 0; it < 2; ++it) {
      const int rb = wave * 2 + it;               // 16-row chunk id, wave-uniform
      const int row = rb * 16 + (lane >> 2);
      const int ch = lane & 3;
      const size_t goffA = (size_t)(m0 + row) * K + k0 + ch * 8;
      const size_t goffB = (size_t)(n0 + row) * K + k0 + ch * 8;
      __builtin_amdgcn_global_load_lds(
          (const __attribute__((address_space(1))) void*)(Ahi + goffA),
          (__attribute__((address_space(3))) void*)(Ah + rb * 512), 16, 0, 0);
      __builtin_amdgcn_global_load_lds(
          (const __attribute__((address_space(1))) void*)(Bhi + goffB),
          (__attribute__((address_space(3))) void*)(Bh + rb * 512), 16, 0, 0);
      if (terms > 1) {
        __builtin_amdgcn_global_load_lds(
            (const __attribute__((address_space(1))) void*)(hLo + goffA),
            (__attribute__((address_space(3))) void*)(Al + rb * 512), 16, 0, 0);
        __builtin_amdgcn_global_load_lds(
            (const __attribute__((address_space(1))) void*)(wqLo + goffB),
            (__attribute__((address_space(3))) void*)(Bl + rb * 512), 16, 0, 0);
      }
    }
    __syncthreads();

    bf16x8 a_h[4], b_h[4], a_l[4], b_l[4];
#pragma unroll
    for (int i = 0; i < 4; ++i)
      a_h[i] = *(const bf16x8*)(Ah + (wr * 64 + i * 16 + lm) * 32 + quad * 8);
#pragma unroll
    for (int j = 0; j < 4; ++j)
      b_h[j] = *(const bf16x8*)(Bh + (wc * 64 + j * 16 + lm) * 32 + quad * 8);
    if (terms > 1) {
#pragma unroll
      for (int i = 0; i < 4; ++i)
        a_l[i] = *(const bf16x8*)(Al + (wr * 64 + i * 16 + lm) * 32 + quad * 8);
#pragma unroll
      for (int j = 0; j < 4; ++j)
        b_l[j] = *(const bf16x8*)(Bl + (wc * 64 + j * 16 + lm) * 32 + quad * 8);
    }
    if (terms > 1) {
#pragma unroll
      for (int i = 0; i < 4; ++i)
#pragma unroll
        for (int j = 0; j < 4; ++j) {
          acc[i][j] = mfma16(a_h[i], b_h[j], acc[i][j]);
          acc[i][j] = mfma16(a_h[i], b_l[j], acc[i][j]);
          acc[i][j] = mfma16(a_l[i], b_h[j], acc[i][j]);
        }
    } else {
#pragma unroll
      for (int i = 0; i < 4; ++i)
#pragma unroll
        for (int j = 0; j < 4; ++j)
          acc[i][j] = mfma16(a_h[i], b_h[j], acc[i][j]);
    }
  }

  // epilogue: C layout col=lane&15, row=quad*4+r; z=0 also reduces n2 per head
  const int hidx = blockIdx.y * 2 + wc;  // head of this wave's 64-col group
#pragma unroll
  for (int i = 0; i < 4; ++i) {
    float nn[4] = {0.f, 0.f, 0.f, 0.f};
#pragma unroll
    for (int j = 0; j < 4; ++j) {
      const int col = n0 + wc * 64 + j * 16 + lm;
      const float bv = bias[col];
#pragma unroll
      for (int r = 0; r < 4; ++r) {
        const int row = m0 + wr * 64 + i * 16 + quad * 4 + r;
        const float val = acc[i][j][r] + bv;
        Cb[(size_t)row * N + col] = f2bf(val);
        nn[r] += val * val;
      }
    }
    if (zsel == 0) {
#pragma unroll
      for (int r = 0; r < 4; ++r)
#pragma unroll
        for (int off = 1; off < 16; off <<= 1) nn[r] += __shfl_xor(nn[r], off, 64);
      if (lm == 0) {
        const int row = m0 + wr * 64 + i * 16 + quad * 4;  // 4 consecutive rows
        const int b = row >> 11, l = row & 2047;
        *(float4*)&n2A[(size_t)(b * 16 + hidx) * 2048 + l] =
            make_float4(nn[0], nn[1], nn[2], nn[3]);
      }
    }
  }
}

// ---------------------------------------------------------------------------
// 4b) pre-transpose V: vB[b,l,h,d] -> vT[bh][d][key]  (64 x 2048 per bh)
// ---------------------------------------------------------------------------
__global__ __launch_bounds__(256) void vtrans_kernel(
    const u16* __restrict__ vB, u16* __restrict__ vT) {
  constexpr int TS = 72;
  __shared__ u16 Ts[64 * TS];
  const int kt = blockIdx.x, bh = blockIdx.y;
  const int b = bh >> 4, h = bh & 15;
  const int tid = threadIdx.x;
  const int row0 = tid >> 3, ch = tid & 7;
  const u16* src = vB + (size_t)b * 2048 * 1024 + h * 64;
#pragma unroll
  for (int it = 0; it < 2; ++it) {
    const int kr = row0 + it * 32;  // local key row
    uint4 v = *(const uint4*)(src + (size_t)(kt * 64 + kr) * 1024 + ch * 8);
    *(uint4*)((char*)Ts + kr * (TS * 2) + ch * 16) = v;
  }
  __syncthreads();
  u16* dst = vT + (size_t)bh * 64 * 2048 + kt * 64;
#pragma unroll
  for (int it = 0; it < 2; ++it) {
    const int d = row0 + it * 32;
    union { uint4 v; u16 s[8]; } u;
#pragma unroll
    for (int j = 0; j < 8; ++j) u.s[j] = Ts[(ch * 8 + j) * TS + d];
    *(uint4*)(dst + (size_t)d * 2048 + ch * 8) = u.v;
  }
}

// ---------------------------------------------------------------------------
// 5) hash bits per (b,h)
// ---------------------------------------------------------------------------
__global__ __launch_bounds__(256) void bits_kernel(
    const float* __restrict__ n2A, const float* __restrict__ dq,
    const float* __restrict__ ha, u8* __restrict__ hqA, u8* __restrict__ hkA) {
  const int bh = blockIdx.x;
  const int tid = threadIdx.x;
  const int wave = tid >> 6, lane = tid & 63;
  __shared__ float red[4];
  const float* n2p = n2A + (size_t)bh * 2048;
  float4 v0 = ((const float4*)n2p)[tid];
  float4 v1 = ((const float4*)n2p)[tid + 256];
  float lmax = fmaxf(fmaxf(fmaxf(v0.x, v0.y), fmaxf(v0.z, v0.w)),
                     fmaxf(fmaxf(v1.x, v1.y), fmaxf(v1.z, v1.w)));
#pragma unroll
  for (int off = 1; off < 64; off <<= 1) lmax = fmaxf(lmax, __shfl_xor(lmax, off, 64));
  if (lane == 0) red[wave] = lmax;
  __syncthreads();
  const float maxn2 = fmaxf(fmaxf(red[0], red[1]), fmaxf(red[2], red[3]));
  const float s = 0.75f / fmaxf(sqrtf(maxn2), 1e-12f);
  const float a64 = ha[64], a65 = ha[65];
#pragma unroll
  for (int it = 0; it < 8; ++it) {
    const int l = it * 256 + tid;
    const float dv = dq[(size_t)bh * 2048 + l];
    const float n2 = n2p[l];
    const float nk2 = s * s * n2;
    const float hkdot = s * dv + (0.5f - nk2) * a64 + (0.5f - nk2 * nk2) * a65;
    hqA[(size_t)bh * 2048 + l] = (dv >= 0.f) ? 1 : 0;
    hkA[(size_t)bh * 2048 + l] = (hkdot >= 0.f) ? 1 : 0;
  }
}

// ---------------------------------------------------------------------------
// 6) flash attention v3: fixed-C softmax (no online rescale, no shuffles),
//    128 q/block (32/wave), global_load_lds dbuf staging w/ XOR swizzle,
//    1 barrier/iter, l via MFMA-with-ones, scale folded into exp2 argument.
// ---------------------------------------------------------------------------
__global__ __launch_bounds__(256, 3) void attn_kernel(
    const u16* __restrict__ qkb, const u16* __restrict__ vT,
    const u8* __restrict__ hqA, const u8* __restrict__ hkA, float* __restrict__ out) {
  __shared__ u16 Ks[2][4096];   // [buf][key(64) x dim(64)], 16B-chunk XOR swizzle
  __shared__ u16 Vs[2][4096];   // [buf][dim(64) x key(64)], same swizzle
  __shared__ u16 Ps[4][2048];   // [wave][qrow(32) x key(64)], same swizzle

  const int qt = blockIdx.x;    // 0..15 (128 queries each)
  const int bh = blockIdx.y;    // 0..31
  const int b = bh >> 4, h = bh & 15;
  const int tid = threadIdx.x, wave = tid >> 6, lane = tid & 63;
  const int quad = lane >> 4, lm = lane & 15;
  const int lx = lm & 7;
  const int r8 = lane >> 3, ch = lane & 7;
  const int q0 = qt * 128;

  const u16* qbase = qkb + (size_t)b * 2048 * 1024 + h * 64;
  const u16* vtb = vT + (size_t)bh * 64 * 2048;
  const u8* hkp = hkA + (size_t)bh * 2048;

  // Q A-frags straight from global (raw; 1/sqrt(DH) folded into exp2 arg)
  bf16x8 aQ[2][2];
#pragma unroll
  for (int s = 0; s < 2; ++s)
#pragma unroll
    for (int c = 0; c < 2; ++c)
      aQ[s][c] = *(const bf16x8*)(qbase +
          (size_t)(q0 + wave * 32 + s * 16 + lm) * 1024 + c * 32 + quad * 8);
  u8 hqb[2][4];
  {
    const u8* hqp = hqA + (size_t)bh * 2048 + q0 + wave * 32;
#pragma unroll
    for (int s = 0; s < 2; ++s)
#pragma unroll
      for (int r = 0; r < 4; ++r) hqb[s][r] = hqp[s * 16 + quad * 4 + r];
  }

  const int srow = wave * 16;  // this wave's 16-row staging slab
  auto stage = [&](int kt, int buf) {
#pragma unroll
    for (int i = 0; i < 2; ++i) {
      const int row = srow + i * 8 + r8;  // key row for K / dim row for V
      const int sw = (ch ^ (row & 7)) * 8;
      __builtin_amdgcn_global_load_lds(
          (const __attribute__((address_space(1))) void*)(
              qbase + (size_t)(kt * 64 + row) * 1024 + sw),
          (__attribute__((address_space(3))) void*)(&Ks[buf][(srow + i * 8) * 64]),
          16, 0, 0);
      __builtin_amdgcn_global_load_lds(
          (const __attribute__((address_space(1))) void*)(
              vtb + (size_t)row * 2048 + kt * 64 + sw),
          (__attribute__((address_space(3))) void*)(&Vs[buf][(srow + i * 8) * 64]),
          16, 0, 0);
    }
  };

  stage(0, 0);

  f32x4 acc_o[2][4], accL[2];
#pragma unroll
  for (int s = 0; s < 2; ++s) {
    accL[s] = {0.f, 0.f, 0.f, 0.f};
#pragma unroll
    for (int j = 0; j < 4; ++j) acc_o[s][j] = {0.f, 0.f, 0.f, 0.f};
  }
  const bf16x8 ones = {0x3F80, 0x3F80, 0x3F80, 0x3F80, 0x3F80, 0x3F80, 0x3F80, 0x3F80};
  const float SCL = 0.18033688f;        // 0.125 * log2(e)
  const float M0 = -4.3280854f;         // -C*log2(e), C = 3
  const float M1 = -1.4430768e4f;       // -(1e4 + C)*log2(e)  -> exp2 underflows to 0

  __syncthreads();  // tile 0 staged (barrier drains vmcnt)

  for (int kt = 0; kt < 32; ++kt) {
    const int cur = kt & 1;
    if (kt < 31) stage(kt + 1, cur ^ 1);

    u8 hkv[4];
#pragma unroll
    for (int nb = 0; nb < 4; ++nb) hkv[nb] = hkp[kt * 64 + nb * 16 + lm];

    // S = Q K^T (raw dot products; scaling folded into exp)
    f32x4 cs[2][4];
#pragma unroll
    for (int s = 0; s < 2; ++s)
#pragma unroll
      for (int nb = 0; nb < 4; ++nb) cs[s][nb] = {0.f, 0.f, 0.f, 0.f};
#pragma unroll
    for (int c = 0; c < 2; ++c)
#pragma unroll
      for (int nb = 0; nb < 4; ++nb) {
        bf16x8 bK = *(const bf16x8*)&Ks[cur][(nb * 16 + lm) * 64 + (((c * 4 + quad) ^ lx) * 8)];
        cs[0][nb] = mfma16(aQ[0][c], bK, cs[0][nb]);
        cs[1][nb] = mfma16(aQ[1][c], bK, cs[1][nb]);
      }

    // p = 2^(s*SCL + msel); write bf16 (truncation) into swizzled Ps
#pragma unroll
    for (int s = 0; s < 2; ++s)
#pragma unroll
      for (int nb = 0; nb < 4; ++nb)
#pragma unroll
        for (int r = 0; r < 4; ++r) {
          const float msel = (hqb[s][r] == hkv[nb]) ? M0 : M1;
          const float p = EXP2(__builtin_fmaf(cs[s][nb][r], SCL, msel));
          const int prow = s * 16 + quad * 4 + r;
          const int pc = (nb * 2 + (lm >> 3)) ^ (prow & 7);
          union { float f; u16 hw[2]; } u;
          u.f = p;
          Ps[wave][prow * 64 + pc * 8 + lx] = u.hw[1];
        }

    // P frags (same-wave round trip; lgkm ordering, no barrier) + l via ones-MFMA
    bf16x8 aP[2][2];
#pragma unroll
    for (int s = 0; s < 2; ++s)
#pragma unroll
      for (int c = 0; c < 2; ++c) {
        aP[s][c] = *(const bf16x8*)&Ps[wave][(s * 16 + lm) * 64 + (((c * 4 + quad) ^ lx) * 8)];
        accL[s] = mfma16(aP[s][c], ones, accL[s]);
      }
    // O += P V
#pragma unroll
    for (int c = 0; c < 2; ++c)
#pragma unroll
      for (int j = 0; j < 4; ++j) {
        bf16x8 bV = *(const bf16x8*)&Vs[cur][(j * 16 + lm) * 64 + (((c * 4 + quad) ^ lx) * 8)];
        acc_o[0][j] = mfma16(aP[0][c], bV, acc_o[0][j]);
        acc_o[1][j] = mfma16(aP[1][c], bV, acc_o[1][j]);
      }

    __syncthreads();  // prev-tile reads done + next-tile staging drained
  }

#pragma unroll
  for (int s = 0; s < 2; ++s)
#pragma unroll
    for (int r = 0; r < 4; ++r) {
      const float inv = 1.0f / accL[s][r];
      float* op = out + (size_t)(b * 2048 + q0 + wave * 32 + s * 16 + quad * 4 + r) * 1024 + h * 64;
#pragma unroll
      for (int j = 0; j < 4; ++j) op[j * 16 + lm] = acc_o[s][j][r] * inv;
    }
}

// ---------------------------------------------------------------------------
extern "C" void kernel_launch(void* const* d_in, const int* in_sizes, int n_in,
                              void* d_out, int out_size, void* d_ws, size_t ws_size,
                              hipStream_t stream) {
  const float* hidden = (const float*)d_in[0];
  const float* qk_w   = (const float*)d_in[1];
  const float* qk_b   = (const float*)d_in[2];
  const float* v_w    = (const float*)d_in[3];
  const float* v_b    = (const float*)d_in[4];
  const float* hash_a = (const float*)d_in[5];
  float* out = (float*)d_out;

  char* base = (char*)d_ws;
  size_t off = 0;
  auto take = [&](size_t bytes) -> char* {
    char* r = base + off;
    off += (bytes + 255) & ~(size_t)255;
    return r;
  };
  const size_t NH = 4194304;  // B*L*D
  const size_t NW = 1048576;  // D*D
  u16* hHi  = (u16*)take(NH * 2);
  u16* hLo  = (u16*)take(NH * 2);
  u16* wqHi = (u16*)take(NW * 2);
  u16* wqLo = (u16*)take(NW * 2);
  u16* wvHi = (u16*)take(NW * 2);
  u16* wvLo = (u16*)take(NW * 2);
  u16* qkB  = (u16*)take(NH * 2);
  u16* vB   = (u16*)take(NH * 2);
  u16* vT   = (u16*)take(NH * 2);
  double* ca = (double*)take(16 * 1024 * 8);
  float* dq  = (float*)take(65536 * 4);
  float* n2A = (float*)take(65536 * 4);
  u8* hqA = (u8*)take(65536);
  u8* hkA = (u8*)take(65536);

  hipLaunchKernelGGL(split_kernel, dim3(NH / 256), dim3(256), 0, stream, hidden, hHi, hLo, (int)NH);
  hipLaunchKernelGGL(split_kernel, dim3(NW / 256), dim3(256), 0, stream, qk_w, wqHi, wqLo, (int)NW);
  hipLaunchKernelGGL(split_kernel, dim3(NW / 256), dim3(256), 0, stream, v_w, wvHi, wvLo, (int)NW);
  hipLaunchKernelGGL(ca_kernel, dim3(64), dim3(256), 0, stream, qk_w, hash_a, ca);
  hipLaunchKernelGGL(d_kernel, dim3(1024), dim3(256), 0, stream, hidden, ca, dq);
  hipLaunchKernelGGL(gemm_fused, dim3(32, 8, 2), dim3(256), 0, stream,
                     hHi, hLo, wqHi, wqLo, wvHi, qk_b, v_b, qkB, vB, n2A);
  hipLaunchKernelGGL(vtrans_kernel, dim3(32, 32), dim3(256), 0, stream, vB, vT);
  hipLaunchKernelGGL(bits_kernel, dim3(32), dim3(256), 0, stream, n2A, dq, hash_a, hqA, hkA);
  hipLaunchKernelGGL(attn_kernel, dim3(16, 32), dim3(256), 0, stream, qkB, vT, hqA, hkA, out);
}

// Round 6
// 245.784 us; speedup vs baseline: 2.5864x; 1.0458x over previous
//
#include <hip/hip_runtime.h>

typedef unsigned short u16;
typedef unsigned char  u8;
typedef unsigned int   u32;

typedef short bf16x8 __attribute__((ext_vector_type(8)));
typedef float f32x4  __attribute__((ext_vector_type(4)));

#define DEV __device__ __forceinline__

#if __has_builtin(__builtin_amdgcn_exp2f)
#define EXP2(x) __builtin_amdgcn_exp2f(x)
#else
#define EXP2(x) exp2f(x)
#endif

DEV u16 f2bf(float x) {
  u32 u = __builtin_bit_cast(u32, x);
  u32 r = (u + 0x7fffu + ((u >> 16) & 1u)) >> 16;
  return (u16)r;
}
DEV float bf2f(u16 h) {
  u32 u = ((u32)h) << 16;
  return __builtin_bit_cast(float, u);
}
DEV f32x4 mfma16(bf16x8 a, bf16x8 b, f32x4 c) {
  return __builtin_amdgcn_mfma_f32_16x16x32_bf16(a, b, c, 0, 0, 0);
}

// ---------------------------------------------------------------------------
// 1) split fp32 -> bf16 hi/lo
// ---------------------------------------------------------------------------
__global__ __launch_bounds__(256) void split_kernel(
    const float* __restrict__ x, u16* __restrict__ hi, u16* __restrict__ lo, int n) {
  int i = blockIdx.x * 256 + threadIdx.x;
  if (i >= n) return;
  float v = x[i];
  u16 h = f2bf(v);
  hi[i] = h;
  lo[i] = f2bf(v - bf2f(h));
}

// ---------------------------------------------------------------------------
// 2) ca[h][k] = sum_j W[h*64+j][k] * a[j]   (fp64)
// ---------------------------------------------------------------------------
__global__ __launch_bounds__(256) void ca_kernel(
    const float* __restrict__ W, const float* __restrict__ ha, double* __restrict__ ca) {
  int idx = blockIdx.x * 256 + threadIdx.x;  // 16 * 1024
  int h = idx >> 10, k = idx & 1023;
  double s = 0.0;
#pragma unroll 8
  for (int j = 0; j < 64; ++j)
    s += (double)W[(size_t)(h * 64 + j) * 1024 + k] * (double)ha[j];
  ca[idx] = s;
}

// ---------------------------------------------------------------------------
// 3) d[bh][l] = sum_k hidden[row][k] * ca[h][k]   (fp64 acc; exact q-hash sign)
// ---------------------------------------------------------------------------
__global__ __launch_bounds__(256) void d_kernel(
    const float* __restrict__ hid, const double* __restrict__ ca, float* __restrict__ dq) {
  const int row  = blockIdx.x * 4 + (threadIdx.x >> 6);  // 0..4095
  const int lane = threadIdx.x & 63;
  const int b = row >> 11, l = row & 2047;
  double acc[16];
#pragma unroll
  for (int h = 0; h < 16; ++h) acc[h] = 0.0;
  const float* hp = hid + (size_t)row * 1024;
  for (int k = lane; k < 1024; k += 64) {
    const double hv = (double)hp[k];
#pragma unroll
    for (int h = 0; h < 16; ++h) acc[h] += hv * ca[h * 1024 + k];
  }
#pragma unroll
  for (int h = 0; h < 16; ++h) {
    double v = acc[h];
#pragma unroll
    for (int off = 32; off; off >>= 1) v += __shfl_xor(v, off, 64);
    if (lane == 0) dq[(size_t)(b * 16 + h) * 2048 + l] = (float)v;
  }
}

// ---------------------------------------------------------------------------
// 4) fused dual GEMM, grid (32,8,2):
//    z=0: qk[token][col] = hidden @ qk_w^T + qk_b (3-term split-bf16)
//         -> qkB (stride 1024) + n2A (fused per-head sumsq epilogue)
//    z=1: vt[vcol][token] = v_w @ hidden^T + v_b[vcol] (1-term)
//         -> vT (stride 4096) == V^T directly; vtrans kernel deleted.
// ---------------------------------------------------------------------------
__global__ __launch_bounds__(256) void gemm_fused(
    const u16* __restrict__ hHi, const u16* __restrict__ hLo,
    const u16* __restrict__ wqHi, const u16* __restrict__ wqLo,
    const u16* __restrict__ wvHi,
    const float* __restrict__ qk_b, const float* __restrict__ v_b,
    u16* __restrict__ qkB, u16* __restrict__ vT, float* __restrict__ n2A) {
  constexpr int K = 1024;
  __shared__ u16 Ah[128 * 32];
  __shared__ u16 Bh[128 * 32];
  __shared__ u16 Al[128 * 32];
  __shared__ u16 Bl[128 * 32];

  const int zsel = blockIdx.z;
  const int m0 = (zsel ? blockIdx.y : blockIdx.x) * 128;
  const int n0 = (zsel ? blockIdx.x : blockIdx.y) * 128;
  const int CN = zsel ? 4096 : 1024;
  const u16* __restrict__ Ahi = zsel ? wvHi : hHi;
  const u16* __restrict__ Bhi = zsel ? hHi : wqHi;
  u16* __restrict__ Cb = zsel ? vT : qkB;
  const int terms = zsel ? 1 : 3;

  const int tid = threadIdx.x;
  const int wave = tid >> 6, lane = tid & 63;
  const int quad = lane >> 4, lm = lane & 15;
  const int wr = wave >> 1, wc = wave & 1;

  f32x4 acc[4][4];
#pragma unroll
  for (int i = 0; i < 4; ++i)
#pragma unroll
    for (int j = 0; j < 4; ++j) acc[i][j] = {0.f, 0.f, 0.f, 0.f};

  for (int k0 = 0; k0 < K; k0 += 32) {
    __syncthreads();
#pragma unroll
    for (int it = 0; it < 2; ++it) {
      const int rb = wave * 2 + it;               // 16-row chunk id, wave-uniform
      const int row = rb * 16 + (lane >> 2);
      const int ch = lane & 3;
      const size_t goffA = (size_t)(m0 + row) * K + k0 + ch * 8;
      const size_t goffB = (size_t)(n0 + row) * K + k0 + ch * 8;
      __builtin_amdgcn_global_load_lds(
          (const __attribute__((address_space(1))) void*)(Ahi + goffA),
          (__attribute__((address_space(3))) void*)(Ah + rb * 512), 16, 0, 0);
      __builtin_amdgcn_global_load_lds(
          (const __attribute__((address_space(1))) void*)(Bhi + goffB),
          (__attribute__((address_space(3))) void*)(Bh + rb * 512), 16, 0, 0);
      if (terms > 1) {
        __builtin_amdgcn_global_load_lds(
            (const __attribute__((address_space(1))) void*)(hLo + goffA),
            (__attribute__((address_space(3))) void*)(Al + rb * 512), 16, 0, 0);
        __builtin_amdgcn_global_load_lds(
            (const __attribute__((address_space(1))) void*)(wqLo + goffB),
            (__attribute__((address_space(3))) void*)(Bl + rb * 512), 16, 0, 0);
      }
    }
    __syncthreads();

    bf16x8 a_h[4], b_h[4], a_l[4], b_l[4];
#pragma unroll
    for (int i = 0; i < 4; ++i)
      a_h[i] = *(const bf16x8*)(Ah + (wr * 64 + i * 16 + lm) * 32 + quad * 8);
#pragma unroll
    for (int j = 0; j < 4; ++j)
      b_h[j] = *(const bf16x8*)(Bh + (wc * 64 + j * 16 + lm) * 32 + quad * 8);
    if (terms > 1) {
#pragma unroll
      for (int i = 0; i < 4; ++i)
        a_l[i] = *(const bf16x8*)(Al + (wr * 64 + i * 16 + lm) * 32 + quad * 8);
#pragma unroll
      for (int j = 0; j < 4; ++j)
        b_l[j] = *(const bf16x8*)(Bl + (wc * 64 + j * 16 + lm) * 32 + quad * 8);
#pragma unroll
      for (int i = 0; i < 4; ++i)
#pragma unroll
        for (int j = 0; j < 4; ++j) {
          acc[i][j] = mfma16(a_h[i], b_h[j], acc[i][j]);
          acc[i][j] = mfma16(a_h[i], b_l[j], acc[i][j]);
          acc[i][j] = mfma16(a_l[i], b_h[j], acc[i][j]);
        }
    } else {
#pragma unroll
      for (int i = 0; i < 4; ++i)
#pragma unroll
        for (int j = 0; j < 4; ++j)
          acc[i][j] = mfma16(a_h[i], b_h[j], acc[i][j]);
    }
  }

  // epilogue: C layout col=lane&15, row=quad*4+r
  if (zsel == 0) {
    const int hidx = blockIdx.y * 2 + wc;  // head of this wave's 64-col group
#pragma unroll
    for (int i = 0; i < 4; ++i) {
      float nn[4] = {0.f, 0.f, 0.f, 0.f};
#pragma unroll
      for (int j = 0; j < 4; ++j) {
        const int col = n0 + wc * 64 + j * 16 + lm;
        const float bv = qk_b[col];
#pragma unroll
        for (int r = 0; r < 4; ++r) {
          const int row = m0 + wr * 64 + i * 16 + quad * 4 + r;
          const float val = acc[i][j][r] + bv;
          Cb[(size_t)row * CN + col] = f2bf(val);
          nn[r] += val * val;
        }
      }
#pragma unroll
      for (int r = 0; r < 4; ++r)
#pragma unroll
        for (int off = 1; off < 16; off <<= 1) nn[r] += __shfl_xor(nn[r], off, 64);
      if (lm == 0) {
        const int row = m0 + wr * 64 + i * 16 + quad * 4;  // 4 consecutive rows
        const int b = row >> 11, l = row & 2047;
        *(float4*)&n2A[(size_t)(b * 16 + hidx) * 2048 + l] =
            make_float4(nn[0], nn[1], nn[2], nn[3]);
      }
    }
  } else {
#pragma unroll
    for (int i = 0; i < 4; ++i)
#pragma unroll
      for (int r = 0; r < 4; ++r) {
        const int row = m0 + wr * 64 + i * 16 + quad * 4 + r;  // vcol
        const float bv = v_b[row];
#pragma unroll
        for (int j = 0; j < 4; ++j) {
          const int col = n0 + wc * 64 + j * 16 + lm;  // token
          Cb[(size_t)row * CN + col] = f2bf(acc[i][j][r] + bv);
        }
      }
  }
}

// ---------------------------------------------------------------------------
// 5) hash bits per (b,h)
// ---------------------------------------------------------------------------
__global__ __launch_bounds__(256) void bits_kernel(
    const float* __restrict__ n2A, const float* __restrict__ dq,
    const float* __restrict__ ha, u8* __restrict__ hqA, u8* __restrict__ hkA) {
  const int bh = blockIdx.x;
  const int tid = threadIdx.x;
  const int wave = tid >> 6, lane = tid & 63;
  __shared__ float red[4];
  const float* n2p = n2A + (size_t)bh * 2048;
  float4 v0 = ((const float4*)n2p)[tid];
  float4 v1 = ((const float4*)n2p)[tid + 256];
  float lmax = fmaxf(fmaxf(fmaxf(v0.x, v0.y), fmaxf(v0.z, v0.w)),
                     fmaxf(fmaxf(v1.x, v1.y), fmaxf(v1.z, v1.w)));
#pragma unroll
  for (int off = 1; off < 64; off <<= 1) lmax = fmaxf(lmax, __shfl_xor(lmax, off, 64));
  if (lane == 0) red[wave] = lmax;
  __syncthreads();
  const float maxn2 = fmaxf(fmaxf(red[0], red[1]), fmaxf(red[2], red[3]));
  const float s = 0.75f / fmaxf(sqrtf(maxn2), 1e-12f);
  const float a64 = ha[64], a65 = ha[65];
#pragma unroll
  for (int it = 0; it < 8; ++it) {
    const int l = it * 256 + tid;
    const float dv = dq[(size_t)bh * 2048 + l];
    const float n2 = n2p[l];
    const float nk2 = s * s * n2;
    const float hkdot = s * dv + (0.5f - nk2) * a64 + (0.5f - nk2 * nk2) * a65;
    hqA[(size_t)bh * 2048 + l] = (dv >= 0.f) ? 1 : 0;
    hkA[(size_t)bh * 2048 + l] = (hkdot >= 0.f) ? 1 : 0;
  }
}

// ---------------------------------------------------------------------------
// 6) flash attention v4: 64 q/block (16 q/wave), grid (32,32) = 4 blocks/CU
//    (LDS 40 KB), fixed-C softmax, dbuf global_load_lds staging w/ XOR swizzle,
//    1 barrier/iter, l via MFMA-with-ones. vT stride 4096 (from gemm z=1).
// ---------------------------------------------------------------------------
__global__ __launch_bounds__(256, 4) void attn_kernel(
    const u16* __restrict__ qkb, const u16* __restrict__ vT,
    const u8* __restrict__ hqA, const u8* __restrict__ hkA, float* __restrict__ out) {
  __shared__ u16 Ks[2][4096];   // [buf][key(64) x dim(64)], 16B-chunk XOR swizzle
  __shared__ u16 Vs[2][4096];   // [buf][dim(64) x key(64)], same swizzle
  __shared__ u16 Ps[4][1024];   // [wave][qrow(16) x key(64)], same swizzle

  const int qt = blockIdx.x;    // 0..31 (64 queries each)
  const int bh = blockIdx.y;    // 0..31
  const int b = bh >> 4, h = bh & 15;
  const int tid = threadIdx.x, wave = tid >> 6, lane = tid & 63;
  const int quad = lane >> 4, lm = lane & 15;
  const int lx = lm & 7;
  const int r8 = lane >> 3, ch = lane & 7;
  const int q0 = qt * 64;

  const u16* qbase = qkb + (size_t)b * 2048 * 1024 + h * 64;
  const u16* vtb = vT + (size_t)h * 64 * 4096 + b * 2048;  // row stride 4096
  const u8* hkp = hkA + (size_t)bh * 2048;

  // Q A-frags straight from global (raw; 1/sqrt(DH) folded into exp2 arg)
  bf16x8 aQ[2];
#pragma unroll
  for (int c = 0; c < 2; ++c)
    aQ[c] = *(const bf16x8*)(qbase +
        (size_t)(q0 + wave * 16 + lm) * 1024 + c * 32 + quad * 8);
  u8 hqb[4];
  {
    const u8* hqp = hqA + (size_t)bh * 2048 + q0 + wave * 16;
#pragma unroll
    for (int r = 0; r < 4; ++r) hqb[r] = hqp[quad * 4 + r];
  }

  const int srow = wave * 16;  // this wave's 16-row staging slab
  auto stage = [&](int kt, int buf) {
#pragma unroll
    for (int i = 0; i < 2; ++i) {
      const int row = srow + i * 8 + r8;  // key row for K / dim row for V
      const int sw = (ch ^ (row & 7)) * 8;
      __builtin_amdgcn_global_load_lds(
          (const __attribute__((address_space(1))) void*)(
              qbase + (size_t)(kt * 64 + row) * 1024 + sw),
          (__attribute__((address_space(3))) void*)(&Ks[buf][(srow + i * 8) * 64]),
          16, 0, 0);
      __builtin_amdgcn_global_load_lds(
          (const __attribute__((address_space(1))) void*)(
              vtb + (size_t)row * 4096 + kt * 64 + sw),
          (__attribute__((address_space(3))) void*)(&Vs[buf][(srow + i * 8) * 64]),
          16, 0, 0);
    }
  };

  stage(0, 0);

  f32x4 acc_o[4], accL;
  accL = {0.f, 0.f, 0.f, 0.f};
#pragma unroll
  for (int j = 0; j < 4; ++j) acc_o[j] = {0.f, 0.f, 0.f, 0.f};
  const bf16x8 ones = {0x3F80, 0x3F80, 0x3F80, 0x3F80, 0x3F80, 0x3F80, 0x3F80, 0x3F80};
  const float SCL = 0.18033688f;        // 0.125 * log2(e)
  const float M0 = -4.3280854f;         // -C*log2(e), C = 3
  const float M1 = -1.4430768e4f;       // -(1e4 + C)*log2(e)  -> exp2 underflows to 0

  __syncthreads();  // tile 0 staged (barrier drains vmcnt)

  for (int kt = 0; kt < 32; ++kt) {
    const int cur = kt & 1;
    if (kt < 31) stage(kt + 1, cur ^ 1);

    u8 hkv[4];
#pragma unroll
    for (int nb = 0; nb < 4; ++nb) hkv[nb] = hkp[kt * 64 + nb * 16 + lm];

    // S = Q K^T (raw dot products; scaling folded into exp)
    f32x4 cs[4];
#pragma unroll
    for (int nb = 0; nb < 4; ++nb) cs[nb] = {0.f, 0.f, 0.f, 0.f};
#pragma unroll
    for (int c = 0; c < 2; ++c)
#pragma unroll
      for (int nb = 0; nb < 4; ++nb) {
        bf16x8 bK = *(const bf16x8*)&Ks[cur][(nb * 16 + lm) * 64 + (((c * 4 + quad) ^ lx) * 8)];
        cs[nb] = mfma16(aQ[c], bK, cs[nb]);
      }

    // p = 2^(s*SCL + msel); write bf16 (truncation) into swizzled Ps
#pragma unroll
    for (int nb = 0; nb < 4; ++nb)
#pragma unroll
      for (int r = 0; r < 4; ++r) {
        const float msel = (hqb[r] == hkv[nb]) ? M0 : M1;
        const float p = EXP2(__builtin_fmaf(cs[nb][r], SCL, msel));
        const int prow = quad * 4 + r;
        const int pc = (nb * 2 + (lm >> 3)) ^ (prow & 7);
        union { float f; u16 hw[2]; } u;
        u.f = p;
        Ps[wave][prow * 64 + pc * 8 + lx] = u.hw[1];
      }

    // P frags (same-wave round trip; lgkm ordering, no barrier) + l via ones-MFMA
    bf16x8 aP[2];
#pragma unroll
    for (int c = 0; c < 2; ++c) {
      aP[c] = *(const bf16x8*)&Ps[wave][lm * 64 + (((c * 4 + quad) ^ lx) * 8)];
      accL = mfma16(aP[c], ones, accL);
    }
    // O += P V
#pragma unroll
    for (int c = 0; c < 2; ++c)
#pragma unroll
      for (int j = 0; j < 4; ++j) {
        bf16x8 bV = *(const bf16x8*)&Vs[cur][(j * 16 + lm) * 64 + (((c * 4 + quad) ^ lx) * 8)];
        acc_o[j] = mfma16(aP[c], bV, acc_o[j]);
      }

    __syncthreads();  // prev-tile reads done + next-tile staging drained
  }

#pragma unroll
  for (int r = 0; r < 4; ++r) {
    const float inv = 1.0f / accL[r];
    float* op = out + (size_t)(b * 2048 + q0 + wave * 16 + quad * 4 + r) * 1024 + h * 64;
#pragma unroll
    for (int j = 0; j < 4; ++j) op[j * 16 + lm] = acc_o[j][r] * inv;
  }
}

// ---------------------------------------------------------------------------
extern "C" void kernel_launch(void* const* d_in, const int* in_sizes, int n_in,
                              void* d_out, int out_size, void* d_ws, size_t ws_size,
                              hipStream_t stream) {
  const float* hidden = (const float*)d_in[0];
  const float* qk_w   = (const float*)d_in[1];
  const float* qk_b   = (const float*)d_in[2];
  const float* v_w    = (const float*)d_in[3];
  const float* v_b    = (const float*)d_in[4];
  const float* hash_a = (const float*)d_in[5];
  float* out = (float*)d_out;

  char* base = (char*)d_ws;
  size_t off = 0;
  auto take = [&](size_t bytes) -> char* {
    char* r = base + off;
    off += (bytes + 255) & ~(size_t)255;
    return r;
  };
  const size_t NH = 4194304;  // B*L*D
  const size_t NW = 1048576;  // D*D
  u16* hHi  = (u16*)take(NH * 2);
  u16* hLo  = (u16*)take(NH * 2);
  u16* wqHi = (u16*)take(NW * 2);
  u16* wqLo = (u16*)take(NW * 2);
  u16* wvHi = (u16*)take(NW * 2);
  u16* wvLo = (u16*)take(NW * 2);
  u16* qkB  = (u16*)take(NH * 2);
  u16* vT   = (u16*)take(NH * 2);
  double* ca = (double*)take(16 * 1024 * 8);
  float* dq  = (float*)take(65536 * 4);
  float* n2A = (float*)take(65536 * 4);
  u8* hqA = (u8*)take(65536);
  u8* hkA = (u8*)take(65536);

  hipLaunchKernelGGL(split_kernel, dim3(NH / 256), dim3(256), 0, stream, hidden, hHi, hLo, (int)NH);
  hipLaunchKernelGGL(split_kernel, dim3(NW / 256), dim3(256), 0, stream, qk_w, wqHi, wqLo, (int)NW);
  hipLaunchKernelGGL(split_kernel, dim3(NW / 256), dim3(256), 0, stream, v_w, wvHi, wvLo, (int)NW);
  hipLaunchKernelGGL(ca_kernel, dim3(64), dim3(256), 0, stream, qk_w, hash_a, ca);
  hipLaunchKernelGGL(d_kernel, dim3(1024), dim3(256), 0, stream, hidden, ca, dq);
  hipLaunchKernelGGL(gemm_fused, dim3(32, 8, 2), dim3(256), 0, stream,
                     hHi, hLo, wqHi, wqLo, wvHi, qk_b, v_b, qkB, vT, n2A);
  hipLaunchKernelGGL(bits_kernel, dim3(32), dim3(256), 0, stream, n2A, dq, hash_a, hqA, hkA);
  hipLaunchKernelGGL(attn_kernel, dim3(32, 32), dim3(256), 0, stream, qkB, vT, hqA, hkA, out);
}

// Round 7
// 229.947 us; speedup vs baseline: 2.7645x; 1.0689x over previous
//
#include <hip/hip_runtime.h>

typedef unsigned short u16;
typedef unsigned char  u8;
typedef unsigned int   u32;

typedef short bf16x8 __attribute__((ext_vector_type(8)));
typedef float f32x4  __attribute__((ext_vector_type(4)));

#define DEV __device__ __forceinline__

#if __has_builtin(__builtin_amdgcn_exp2f)
#define EXP2(x) __builtin_amdgcn_exp2f(x)
#else
#define EXP2(x) exp2f(x)
#endif

DEV u16 f2bf(float x) {
  u32 u = __builtin_bit_cast(u32, x);
  u32 r = (u + 0x7fffu + ((u >> 16) & 1u)) >> 16;
  return (u16)r;
}
DEV float bf2f(u16 h) {
  u32 u = ((u32)h) << 16;
  return __builtin_bit_cast(float, u);
}
DEV f32x4 mfma16(bf16x8 a, bf16x8 b, f32x4 c) {
  return __builtin_amdgcn_mfma_f32_16x16x32_bf16(a, b, c, 0, 0, 0);
}

#define GLDS(gptr, lptr)                                                  \
  __builtin_amdgcn_global_load_lds(                                       \
      (const __attribute__((address_space(1))) void*)(gptr),              \
      (__attribute__((address_space(3))) void*)(lptr), 16, 0, 0)

// ---------------------------------------------------------------------------
// 1) one-shot split: hidden -> hi/lo, qk_w -> hi/lo, v_w -> hi only
// ---------------------------------------------------------------------------
__global__ __launch_bounds__(256) void split3_kernel(
    const float* __restrict__ hid, const float* __restrict__ wq,
    const float* __restrict__ wv,
    u16* __restrict__ hHi, u16* __restrict__ hLo,
    u16* __restrict__ wqHi, u16* __restrict__ wqLo, u16* __restrict__ wvHi) {
  const int NH = 4194304, NW = 1048576;
  int i = blockIdx.x * 256 + threadIdx.x;
  if (i < NH) {
    float v = hid[i];
    u16 t = f2bf(v);
    hHi[i] = t;
    hLo[i] = f2bf(v - bf2f(t));
  } else if (i < NH + NW) {
    int j = i - NH;
    float v = wq[j];
    u16 t = f2bf(v);
    wqHi[j] = t;
    wqLo[j] = f2bf(v - bf2f(t));
  } else {
    int j = i - NH - NW;
    wvHi[j] = f2bf(wv[j]);
  }
}

// ---------------------------------------------------------------------------
// 2) ca[h][k] = sum_j W[h*64+j][k] * a[j]   (fp64)
// ---------------------------------------------------------------------------
__global__ __launch_bounds__(256) void ca_kernel(
    const float* __restrict__ W, const float* __restrict__ ha, double* __restrict__ ca) {
  int idx = blockIdx.x * 256 + threadIdx.x;  // 16 * 1024
  int h = idx >> 10, k = idx & 1023;
  double s = 0.0;
#pragma unroll 8
  for (int j = 0; j < 64; ++j)
    s += (double)W[(size_t)(h * 64 + j) * 1024 + k] * (double)ha[j];
  ca[idx] = s;
}

// ---------------------------------------------------------------------------
// 3) d[bh][l] = sum_k hidden[row][k] * ca[h][k]   (fp64 acc; exact q-hash sign)
// ---------------------------------------------------------------------------
__global__ __launch_bounds__(256) void d_kernel(
    const float* __restrict__ hid, const double* __restrict__ ca, float* __restrict__ dq) {
  const int row  = blockIdx.x * 4 + (threadIdx.x >> 6);  // 0..4095
  const int lane = threadIdx.x & 63;
  const int b = row >> 11, l = row & 2047;
  double acc[16];
#pragma unroll
  for (int h = 0; h < 16; ++h) acc[h] = 0.0;
  const float* hp = hid + (size_t)row * 1024;
  for (int k = lane; k < 1024; k += 64) {
    const double hv = (double)hp[k];
#pragma unroll
    for (int h = 0; h < 16; ++h) acc[h] += hv * ca[h * 1024 + k];
  }
#pragma unroll
  for (int h = 0; h < 16; ++h) {
    double v = acc[h];
#pragma unroll
    for (int off = 32; off; off >>= 1) v += __shfl_xor(v, off, 64);
    if (lane == 0) dq[(size_t)(b * 16 + h) * 2048 + l] = (float)v;
  }
}

// ---------------------------------------------------------------------------
// 4) dual-output GEMM, grid (64,8), 2 blocks/CU, attn-style dbuf prefetch:
//    qk[tok][col] = hidden @ qk_w^T + qk_b  (3-term split)  -> qkB + n2A
//    vt[vcol][tok] = v_w @ hidden^T + v_b                  -> vT (stride 4096)
//    Per block: 64-token x 128-col tiles; wv B-frags == qk A-frags (shared).
//    One __syncthreads per K-step; stage(k+1) issued before compute.
// ---------------------------------------------------------------------------
__global__ __launch_bounds__(256, 2) void gemm_fused(
    const u16* __restrict__ hHi, const u16* __restrict__ hLo,
    const u16* __restrict__ wqHi, const u16* __restrict__ wqLo,
    const u16* __restrict__ wvHi,
    const float* __restrict__ qk_b, const float* __restrict__ v_b,
    u16* __restrict__ qkB, u16* __restrict__ vT, float* __restrict__ n2A) {
  constexpr int K = 1024;
  // slots (u16): Ah 0, Al 2048, Bh 4096, Bl 8192, Wh 12288; buf stride 16384
  __shared__ u16 S[2][16384];
  const int tid = threadIdx.x, wave = tid >> 6, lane = tid & 63;
  const int quad = lane >> 4, lm = lane & 15;
  const int wr = wave >> 1, wc = wave & 1;
  const int m0 = blockIdx.x * 64, n0 = blockIdx.y * 128;
  const int ch = lane & 3, rA = lane >> 2;

  auto stage = [&](int kt, int buf) {
    const int k0 = kt * 32;
    const int rowA = wave * 16 + rA;
    GLDS(hHi + (size_t)(m0 + rowA) * K + k0 + ch * 8, &S[buf][0 + wave * 512]);
    GLDS(hLo + (size_t)(m0 + rowA) * K + k0 + ch * 8, &S[buf][2048 + wave * 512]);
#pragma unroll
    for (int it = 0; it < 2; ++it) {
      const int rb = wave * 2 + it;
      const int row = rb * 16 + rA;
      GLDS(wqHi + (size_t)(n0 + row) * K + k0 + ch * 8, &S[buf][4096 + rb * 512]);
      GLDS(wqLo + (size_t)(n0 + row) * K + k0 + ch * 8, &S[buf][8192 + rb * 512]);
      GLDS(wvHi + (size_t)(n0 + row) * K + k0 + ch * 8, &S[buf][12288 + rb * 512]);
    }
  };

  f32x4 aq[2][4], av[4][2];
#pragma unroll
  for (int i = 0; i < 2; ++i)
#pragma unroll
    for (int j = 0; j < 4; ++j) aq[i][j] = {0.f, 0.f, 0.f, 0.f};
#pragma unroll
  for (int i = 0; i < 4; ++i)
#pragma unroll
    for (int j = 0; j < 2; ++j) av[i][j] = {0.f, 0.f, 0.f, 0.f};

  stage(0, 0);
  __syncthreads();

  for (int kt = 0; kt < 32; ++kt) {
    const int cur = kt & 1;
    if (kt < 31) stage(kt + 1, cur ^ 1);

    bf16x8 a_h[2], a_l[2], b_h[4], b_l[4], w_h[4];
#pragma unroll
    for (int i = 0; i < 2; ++i) {
      a_h[i] = *(const bf16x8*)&S[cur][(wr * 32 + i * 16 + lm) * 32 + quad * 8];
      a_l[i] = *(const bf16x8*)&S[cur][2048 + (wr * 32 + i * 16 + lm) * 32 + quad * 8];
    }
#pragma unroll
    for (int j = 0; j < 4; ++j) {
      b_h[j] = *(const bf16x8*)&S[cur][4096 + (wc * 64 + j * 16 + lm) * 32 + quad * 8];
      b_l[j] = *(const bf16x8*)&S[cur][8192 + (wc * 64 + j * 16 + lm) * 32 + quad * 8];
      w_h[j] = *(const bf16x8*)&S[cur][12288 + (wc * 64 + j * 16 + lm) * 32 + quad * 8];
    }
#pragma unroll
    for (int i = 0; i < 2; ++i)
#pragma unroll
      for (int j = 0; j < 4; ++j) {
        aq[i][j] = mfma16(a_h[i], b_h[j], aq[i][j]);
        aq[i][j] = mfma16(a_h[i], b_l[j], aq[i][j]);
        aq[i][j] = mfma16(a_l[i], b_h[j], aq[i][j]);
      }
#pragma unroll
    for (int iv = 0; iv < 4; ++iv)
#pragma unroll
      for (int jv = 0; jv < 2; ++jv)
        av[iv][jv] = mfma16(w_h[iv], a_h[jv], av[iv][jv]);

    __syncthreads();
  }

  // qk epilogue + fused per-head n2 (wc-block == one head: cols n0+wc*64..+63)
  const int hidx = blockIdx.y * 2 + wc;
#pragma unroll
  for (int i = 0; i < 2; ++i) {
    float nn[4] = {0.f, 0.f, 0.f, 0.f};
#pragma unroll
    for (int j = 0; j < 4; ++j) {
      const int col = n0 + wc * 64 + j * 16 + lm;
      const float bv = qk_b[col];
#pragma unroll
      for (int r = 0; r < 4; ++r) {
        const int row = m0 + wr * 32 + i * 16 + quad * 4 + r;
        const float val = aq[i][j][r] + bv;
        qkB[(size_t)row * 1024 + col] = f2bf(val);
        nn[r] += val * val;
      }
    }
#pragma unroll
    for (int r = 0; r < 4; ++r)
#pragma unroll
      for (int off = 1; off < 16; off <<= 1) nn[r] += __shfl_xor(nn[r], off, 64);
    if (lm == 0) {
      const int row = m0 + wr * 32 + i * 16 + quad * 4;  // 4 consecutive rows
      const int b = row >> 11, l = row & 2047;
      *(float4*)&n2A[(size_t)(b * 16 + hidx) * 2048 + l] =
          make_float4(nn[0], nn[1], nn[2], nn[3]);
    }
  }
  // v epilogue: vT[vcol][token], token contiguous over lm
#pragma unroll
  for (int iv = 0; iv < 4; ++iv)
#pragma unroll
    for (int r = 0; r < 4; ++r) {
      const int vcol = n0 + wc * 64 + iv * 16 + quad * 4 + r;
      const float bv = v_b[vcol];
#pragma unroll
      for (int jv = 0; jv < 2; ++jv) {
        const int tok = m0 + wr * 32 + jv * 16 + lm;
        vT[(size_t)vcol * 4096 + tok] = f2bf(av[iv][jv][r] + bv);
      }
    }
}

// ---------------------------------------------------------------------------
// 5) hash bits per (b,h)
// ---------------------------------------------------------------------------
__global__ __launch_bounds__(256) void bits_kernel(
    const float* __restrict__ n2A, const float* __restrict__ dq,
    const float* __restrict__ ha, u8* __restrict__ hqA, u8* __restrict__ hkA) {
  const int bh = blockIdx.x;
  const int tid = threadIdx.x;
  const int wave = tid >> 6, lane = tid & 63;
  __shared__ float red[4];
  const float* n2p = n2A + (size_t)bh * 2048;
  float4 v0 = ((const float4*)n2p)[tid];
  float4 v1 = ((const float4*)n2p)[tid + 256];
  float lmax = fmaxf(fmaxf(fmaxf(v0.x, v0.y), fmaxf(v0.z, v0.w)),
                     fmaxf(fmaxf(v1.x, v1.y), fmaxf(v1.z, v1.w)));
#pragma unroll
  for (int off = 1; off < 64; off <<= 1) lmax = fmaxf(lmax, __shfl_xor(lmax, off, 64));
  if (lane == 0) red[wave] = lmax;
  __syncthreads();
  const float maxn2 = fmaxf(fmaxf(red[0], red[1]), fmaxf(red[2], red[3]));
  const float s = 0.75f / fmaxf(sqrtf(maxn2), 1e-12f);
  const float a64 = ha[64], a65 = ha[65];
#pragma unroll
  for (int it = 0; it < 8; ++it) {
    const int l = it * 256 + tid;
    const float dv = dq[(size_t)bh * 2048 + l];
    const float n2 = n2p[l];
    const float nk2 = s * s * n2;
    const float hkdot = s * dv + (0.5f - nk2) * a64 + (0.5f - nk2 * nk2) * a65;
    hqA[(size_t)bh * 2048 + l] = (dv >= 0.f) ? 1 : 0;
    hkA[(size_t)bh * 2048 + l] = (hkdot >= 0.f) ? 1 : 0;
  }
}

// ---------------------------------------------------------------------------
// 6) flash attention v4: 64 q/block (16 q/wave), grid (32,32) = 4 blocks/CU
//    (LDS 40 KB), fixed-C softmax, dbuf global_load_lds staging w/ XOR swizzle,
//    1 barrier/iter, l via MFMA-with-ones. vT stride 4096 (from gemm).
// ---------------------------------------------------------------------------
__global__ __launch_bounds__(256, 4) void attn_kernel(
    const u16* __restrict__ qkb, const u16* __restrict__ vT,
    const u8* __restrict__ hqA, const u8* __restrict__ hkA, float* __restrict__ out) {
  __shared__ u16 Ks[2][4096];   // [buf][key(64) x dim(64)], 16B-chunk XOR swizzle
  __shared__ u16 Vs[2][4096];   // [buf][dim(64) x key(64)], same swizzle
  __shared__ u16 Ps[4][1024];   // [wave][qrow(16) x key(64)], same swizzle

  const int qt = blockIdx.x;    // 0..31 (64 queries each)
  const int bh = blockIdx.y;    // 0..31
  const int b = bh >> 4, h = bh & 15;
  const int tid = threadIdx.x, wave = tid >> 6, lane = tid & 63;
  const int quad = lane >> 4, lm = lane & 15;
  const int lx = lm & 7;
  const int r8 = lane >> 3, ch = lane & 7;
  const int q0 = qt * 64;

  const u16* qbase = qkb + (size_t)b * 2048 * 1024 + h * 64;
  const u16* vtb = vT + (size_t)h * 64 * 4096 + b * 2048;  // row stride 4096
  const u8* hkp = hkA + (size_t)bh * 2048;

  // Q A-frags straight from global (raw; 1/sqrt(DH) folded into exp2 arg)
  bf16x8 aQ[2];
#pragma unroll
  for (int c = 0; c < 2; ++c)
    aQ[c] = *(const bf16x8*)(qbase +
        (size_t)(q0 + wave * 16 + lm) * 1024 + c * 32 + quad * 8);
  u8 hqb[4];
  {
    const u8* hqp = hqA + (size_t)bh * 2048 + q0 + wave * 16;
#pragma unroll
    for (int r = 0; r < 4; ++r) hqb[r] = hqp[quad * 4 + r];
  }

  const int srow = wave * 16;  // this wave's 16-row staging slab
  auto stage = [&](int kt, int buf) {
#pragma unroll
    for (int i = 0; i < 2; ++i) {
      const int row = srow + i * 8 + r8;  // key row for K / dim row for V
      const int sw = (ch ^ (row & 7)) * 8;
      GLDS(qbase + (size_t)(kt * 64 + row) * 1024 + sw, &Ks[buf][(srow + i * 8) * 64]);
      GLDS(vtb + (size_t)row * 4096 + kt * 64 + sw, &Vs[buf][(srow + i * 8) * 64]);
    }
  };

  stage(0, 0);

  f32x4 acc_o[4], accL;
  accL = {0.f, 0.f, 0.f, 0.f};
#pragma unroll
  for (int j = 0; j < 4; ++j) acc_o[j] = {0.f, 0.f, 0.f, 0.f};
  const bf16x8 ones = {0x3F80, 0x3F80, 0x3F80, 0x3F80, 0x3F80, 0x3F80, 0x3F80, 0x3F80};
  const float SCL = 0.18033688f;        // 0.125 * log2(e)
  const float M0 = -4.3280854f;         // -C*log2(e), C = 3
  const float M1 = -1.4430768e4f;       // -(1e4 + C)*log2(e)  -> exp2 underflows to 0

  __syncthreads();  // tile 0 staged (barrier drains vmcnt)

  for (int kt = 0; kt < 32; ++kt) {
    const int cur = kt & 1;
    if (kt < 31) stage(kt + 1, cur ^ 1);

    u8 hkv[4];
#pragma unroll
    for (int nb = 0; nb < 4; ++nb) hkv[nb] = hkp[kt * 64 + nb * 16 + lm];

    // S = Q K^T (raw dot products; scaling folded into exp)
    f32x4 cs[4];
#pragma unroll
    for (int nb = 0; nb < 4; ++nb) cs[nb] = {0.f, 0.f, 0.f, 0.f};
#pragma unroll
    for (int c = 0; c < 2; ++c)
#pragma unroll
      for (int nb = 0; nb < 4; ++nb) {
        bf16x8 bK = *(const bf16x8*)&Ks[cur][(nb * 16 + lm) * 64 + (((c * 4 + quad) ^ lx) * 8)];
        cs[nb] = mfma16(aQ[c], bK, cs[nb]);
      }

    // p = 2^(s*SCL + msel); write bf16 (truncation) into swizzled Ps
#pragma unroll
    for (int nb = 0; nb < 4; ++nb)
#pragma unroll
      for (int r = 0; r < 4; ++r) {
        const float msel = (hqb[r] == hkv[nb]) ? M0 : M1;
        const float p = EXP2(__builtin_fmaf(cs[nb][r], SCL, msel));
        const int prow = quad * 4 + r;
        const int pc = (nb * 2 + (lm >> 3)) ^ (prow & 7);
        union { float f; u16 hw[2]; } u;
        u.f = p;
        Ps[wave][prow * 64 + pc * 8 + lx] = u.hw[1];
      }

    // P frags (same-wave round trip; lgkm ordering, no barrier) + l via ones-MFMA
    bf16x8 aP[2];
#pragma unroll
    for (int c = 0; c < 2; ++c) {
      aP[c] = *(const bf16x8*)&Ps[wave][lm * 64 + (((c * 4 + quad) ^ lx) * 8)];
      accL = mfma16(aP[c], ones, accL);
    }
    // O += P V
#pragma unroll
    for (int c = 0; c < 2; ++c)
#pragma unroll
      for (int j = 0; j < 4; ++j) {
        bf16x8 bV = *(const bf16x8*)&Vs[cur][(j * 16 + lm) * 64 + (((c * 4 + quad) ^ lx) * 8)];
        acc_o[j] = mfma16(aP[c], bV, acc_o[j]);
      }

    __syncthreads();  // prev-tile reads done + next-tile staging drained
  }

#pragma unroll
  for (int r = 0; r < 4; ++r) {
    const float inv = 1.0f / accL[r];
    float* op = out + (size_t)(b * 2048 + q0 + wave * 16 + quad * 4 + r) * 1024 + h * 64;
#pragma unroll
    for (int j = 0; j < 4; ++j) op[j * 16 + lm] = acc_o[j][r] * inv;
  }
}

// ---------------------------------------------------------------------------
extern "C" void kernel_launch(void* const* d_in, const int* in_sizes, int n_in,
                              void* d_out, int out_size, void* d_ws, size_t ws_size,
                              hipStream_t stream) {
  const float* hidden = (const float*)d_in[0];
  const float* qk_w   = (const float*)d_in[1];
  const float* qk_b   = (const float*)d_in[2];
  const float* v_w    = (const float*)d_in[3];
  const float* v_b    = (const float*)d_in[4];
  const float* hash_a = (const float*)d_in[5];
  float* out = (float*)d_out;

  char* base = (char*)d_ws;
  size_t off = 0;
  auto take = [&](size_t bytes) -> char* {
    char* r = base + off;
    off += (bytes + 255) & ~(size_t)255;
    return r;
  };
  const size_t NH = 4194304;  // B*L*D
  const size_t NW = 1048576;  // D*D
  u16* hHi  = (u16*)take(NH * 2);
  u16* hLo  = (u16*)take(NH * 2);
  u16* wqHi = (u16*)take(NW * 2);
  u16* wqLo = (u16*)take(NW * 2);
  u16* wvHi = (u16*)take(NW * 2);
  u16* qkB  = (u16*)take(NH * 2);
  u16* vT   = (u16*)take(NH * 2);
  double* ca = (double*)take(16 * 1024 * 8);
  float* dq  = (float*)take(65536 * 4);
  float* n2A = (float*)take(65536 * 4);
  u8* hqA = (u8*)take(65536);
  u8* hkA = (u8*)take(65536);

  hipLaunchKernelGGL(split3_kernel, dim3((NH + 2 * NW) / 256), dim3(256), 0, stream,
                     hidden, qk_w, v_w, hHi, hLo, wqHi, wqLo, wvHi);
  hipLaunchKernelGGL(ca_kernel, dim3(64), dim3(256), 0, stream, qk_w, hash_a, ca);
  hipLaunchKernelGGL(d_kernel, dim3(1024), dim3(256), 0, stream, hidden, ca, dq);
  hipLaunchKernelGGL(gemm_fused, dim3(64, 8), dim3(256), 0, stream,
                     hHi, hLo, wqHi, wqLo, wvHi, qk_b, v_b, qkB, vT, n2A);
  hipLaunchKernelGGL(bits_kernel, dim3(32), dim3(256), 0, stream, n2A, dq, hash_a, hqA, hkA);
  hipLaunchKernelGGL(attn_kernel, dim3(32, 32), dim3(256), 0, stream, qkB, vT, hqA, hkA, out);
}